// Round 1
// baseline (813.820 us; speedup 1.0000x reference)
//
#include <hip/hip_runtime.h>

// Problem constants
#define B_SZ   64
#define S_LEN  200
#define H_DIM  1024
#define NHEAD  16
#define HDIM   64
#define FF_DIM 4096
#define NROWS  (B_SZ * S_LEN)   // 12800

typedef __bf16 bf16x8 __attribute__((ext_vector_type(8)));
typedef float  f32x4  __attribute__((ext_vector_type(4)));

#define GLOBAL_AS __attribute__((address_space(1)))
#define LDS_AS    __attribute__((address_space(3)))

__device__ __forceinline__ void g2lds16(const void* g, void* l) {
  __builtin_amdgcn_global_load_lds((const GLOBAL_AS void*)g, (LDS_AS void*)l, 16, 0, 0);
}

__device__ __forceinline__ float b2f(ushort u) {
  return __uint_as_float(((unsigned int)u) << 16);
}
__device__ __forceinline__ ushort f2b(float f) {
  unsigned int u = __float_as_uint(f);
  u += 0x7fffu + ((u >> 16) & 1u);   // RNE
  return (ushort)(u >> 16);
}
__device__ __forceinline__ bf16x8 ld_g16(const ushort* p) {   // 16B global load
  union { uint4 u; bf16x8 v; } r; r.u = *(const uint4*)p; return r.v;
}
__device__ __forceinline__ bf16x8 ld_lds8x2(const ushort* p) { // 2x ds_read_b64
  union { uint2 u[2]; bf16x8 v; } r;
  r.u[0] = *(const uint2*)p;
  r.u[1] = *(const uint2*)(p + 4);
  return r.v;
}

// ---------------------------------------------------------------------------
// Transpose fp32 [K,N] -> bf16 [N,K]
// ---------------------------------------------------------------------------
__global__ __launch_bounds__(256) void transpose_to_bf16(
    const float* __restrict__ w, ushort* __restrict__ wt, int K, int N) {
  __shared__ float tile[32][33];
  int nb = blockIdx.x * 32, kb = blockIdx.y * 32;
  int tx = threadIdx.x, ty = threadIdx.y;  // 32 x 8
#pragma unroll
  for (int i = 0; i < 4; ++i) {
    int k = kb + ty + i * 8;
    tile[ty + i * 8][tx] = w[(size_t)k * N + nb + tx];
  }
  __syncthreads();
#pragma unroll
  for (int i = 0; i < 4; ++i) {
    int n = nb + ty + i * 8;
    wt[(size_t)n * K + kb + tx] = f2b(tile[tx][ty + i * 8]);
  }
}

// ---------------------------------------------------------------------------
// Concat 3 biases of 1024 into one 3072 vector
// ---------------------------------------------------------------------------
__global__ void concat_bias(const float* __restrict__ bq, const float* __restrict__ bk,
                            const float* __restrict__ bv, float* __restrict__ o) {
  int i = blockIdx.x * 256 + threadIdx.x;
  if (i < 1024) o[i] = bq[i];
  else if (i < 2048) o[i] = bk[i - 1024];
  else if (i < 3072) o[i] = bv[i - 2048];
}

// ---------------------------------------------------------------------------
// pos rows 199..398 (the causal-reachable range) -> bf16 [200][64]
// ---------------------------------------------------------------------------
__global__ void pos_to_bf16(const float* __restrict__ pos, ushort* __restrict__ pb) {
  int i = blockIdx.x * 256 + threadIdx.x;   // 50 blocks x 256 = 12800
  pb[i] = f2b(pos[(size_t)199 * 64 + i]);
}

// ---------------------------------------------------------------------------
// LayerNorm (fp32 in) -> bf16 out.  HAS_TIME: += time[r]*wt[c] + bt[c]
// ---------------------------------------------------------------------------
template <int HAS_TIME>
__global__ __launch_bounds__(256) void ln_kernel(
    const float* __restrict__ x, const float* __restrict__ g, const float* __restrict__ be,
    const float* __restrict__ tv, const float* __restrict__ wt, const float* __restrict__ bt,
    ushort* __restrict__ out) {
  int r = blockIdx.x, t = threadIdx.x;
  const float4* xr = (const float4*)(x + (size_t)r * H_DIM);
  float4 xv = xr[t];
  float s  = xv.x + xv.y + xv.z + xv.w;
  float s2 = xv.x * xv.x + xv.y * xv.y + xv.z * xv.z + xv.w * xv.w;
#pragma unroll
  for (int off = 32; off; off >>= 1) {
    s  += __shfl_xor(s, off);
    s2 += __shfl_xor(s2, off);
  }
  __shared__ float red[8];
  int lane = t & 63, wid = t >> 6;
  if (lane == 0) { red[wid] = s; red[4 + wid] = s2; }
  __syncthreads();
  float S  = red[0] + red[1] + red[2] + red[3];
  float S2 = red[4] + red[5] + red[6] + red[7];
  float m    = S * (1.0f / H_DIM);
  float var  = S2 * (1.0f / H_DIM) - m * m;
  float rstd = rsqrtf(var + 1e-5f);
  float tval = HAS_TIME ? tv[r] : 0.0f;
  float4 gv = ((const float4*)g)[t];
  float4 bv = ((const float4*)be)[t];
  float v0 = (xv.x - m) * rstd * gv.x + bv.x;
  float v1 = (xv.y - m) * rstd * gv.y + bv.y;
  float v2 = (xv.z - m) * rstd * gv.z + bv.z;
  float v3 = (xv.w - m) * rstd * gv.w + bv.w;
  if (HAS_TIME) {
    float4 wv = ((const float4*)wt)[t];
    float4 btv = ((const float4*)bt)[t];
    v0 += tval * wv.x + btv.x;
    v1 += tval * wv.y + btv.y;
    v2 += tval * wv.z + btv.z;
    v3 += tval * wv.w + btv.w;
  }
  ushort4 o;
  o.x = f2b(v0); o.y = f2b(v1); o.z = f2b(v2); o.w = f2b(v3);
  ((ushort4*)(out + (size_t)r * H_DIM))[t] = o;
}

// ---------------------------------------------------------------------------
// Old 128x128 GEMM (kept for FF2 where chunked-M makes 256^2 grids too small)
// ---------------------------------------------------------------------------
template <int EPI>
__global__ __launch_bounds__(256) void gemm_bt(
    const ushort* __restrict__ A, const ushort* __restrict__ Bt,
    const float* __restrict__ bias, void* __restrict__ Cv,
    const float* __restrict__ resid, int M, int N, int K) {
  __shared__ __align__(16) ushort As[2 * 128 * 32];   // [kh][row][32]
  __shared__ __align__(16) ushort Bs[2 * 128 * 32];
  int t = threadIdx.x;
  int lane = t & 63, wave = t >> 6;
  int wm = wave >> 1, wn = wave & 1;
  int r15 = lane & 15, quad = lane >> 4;
  size_t row0 = (size_t)blockIdx.y * 128;
  size_t col0 = (size_t)blockIdx.x * 128;

  int srow = (lane >> 2), scol = (lane & 3) * 8;
  const ushort* ga0 = A  + (row0 + wave * 32 +      srow) * K + scol;
  const ushort* ga1 = A  + (row0 + wave * 32 + 16 + srow) * K + scol;
  const ushort* gb0 = Bt + (col0 + wave * 32 +      srow) * K + scol;
  const ushort* gb1 = Bt + (col0 + wave * 32 + 16 + srow) * K + scol;
  ushort* la0 = As + (wave * 32) * 32;
  ushort* la1 = As + (wave * 32 + 16) * 32;
  ushort* lb0 = Bs + (wave * 32) * 32;
  ushort* lb1 = Bs + (wave * 32 + 16) * 32;

  f32x4 acc[4][4] = {};

  for (int k0 = 0; k0 < K; k0 += 64) {
#pragma unroll
    for (int kh = 0; kh < 2; ++kh) {
      int go = k0 + kh * 32, lo = kh * 4096;
      g2lds16(ga0 + go, la0 + lo);
      g2lds16(ga1 + go, la1 + lo);
      g2lds16(gb0 + go, lb0 + lo);
      g2lds16(gb1 + go, lb1 + lo);
    }
    __syncthreads();
#pragma unroll
    for (int kh = 0; kh < 2; ++kh) {
      bf16x8 af[4], bfr[4];
#pragma unroll
      for (int i = 0; i < 4; ++i)
        af[i] = *(const bf16x8*)&As[kh * 4096 + (wm * 64 + i * 16 + r15) * 32 + quad * 8];
#pragma unroll
      for (int j = 0; j < 4; ++j)
        bfr[j] = *(const bf16x8*)&Bs[kh * 4096 + (wn * 64 + j * 16 + r15) * 32 + quad * 8];
#pragma unroll
      for (int i = 0; i < 4; ++i)
#pragma unroll
        for (int j = 0; j < 4; ++j)
          acc[i][j] = __builtin_amdgcn_mfma_f32_16x16x32_bf16(af[i], bfr[j], acc[i][j], 0, 0, 0);
    }
    __syncthreads();
  }

  int mbase = (int)row0 + wm * 64;
  int nbase = (int)col0 + wn * 64;
#pragma unroll
  for (int i = 0; i < 4; ++i) {
#pragma unroll
    for (int j = 0; j < 4; ++j) {
      int col = nbase + j * 16 + r15;
      float bb = bias[col];
#pragma unroll
      for (int ii = 0; ii < 4; ++ii) {
        int row = mbase + i * 16 + quad * 4 + ii;
        size_t idx = (size_t)row * N + col;
        float v = acc[i][j][ii] + bb;
        if constexpr (EPI == 0) {
          ((ushort*)Cv)[idx] = f2b(v);
        } else if constexpr (EPI == 1) {
          float gl = 0.5f * v * (1.0f + erff(v * 0.70710678118f));
          ((ushort*)Cv)[idx] = f2b(gl);
        } else {
          ((float*)Cv)[idx] = v + resid[idx];
        }
      }
    }
  }
}

// ---------------------------------------------------------------------------
// 256x256 8-phase-style GEMM (T2+T3+T4+T5 stack, plain HIP).
//   512 thr = 8 waves (2M x 4N), per-wave C = 128x64.  BK=64.
//   LDS 128 KiB: [buf][A/B][half][kh] planes of [128 rows][32 k] bf16 (8 KB).
//   Each plane is staged (global_load_lds w=16) by EXACTLY the 4 waves that
//   consume it, so a per-wave counted s_waitcnt vmcnt(4) + s_barrier proves
//   the plane resident.  Main loop NEVER drains vmcnt to 0 (T4).
//   4 phases per K-tile (kh x ihalf), 16 MFMA each under setprio(1) (T5).
//   Bank-conflict-free LDS (T2): chunk swizzle slot ^= (row>>1)&3, applied
//   on the GLOBAL source (gload_lds writes linearly, rule #21) and on the
//   ds_read address.  Each 8-lane b128 group then hits 8 distinct bank sets.
//   Requires M%256==0, N%256==0, K%64==0, K>=128.
// ---------------------------------------------------------------------------
template <int IB>
__device__ __forceinline__ void mfma_blk(f32x4 (&acc)[8][4],
                                         const bf16x8 (&af)[4], const bf16x8 (&bfr)[4]) {
#pragma unroll
  for (int i = 0; i < 4; ++i)
#pragma unroll
    for (int j = 0; j < 4; ++j)
      acc[IB + i][j] =
          __builtin_amdgcn_mfma_f32_16x16x32_bf16(af[i], bfr[j], acc[IB + i][j], 0, 0, 0);
}

__device__ __forceinline__ bf16x8 rdfrag(const ushort* plane, int r, int quad) {
  // logical (row r, 16B-slot quad) -> physical slot quad ^ ((r>>1)&3)
  return *(const bf16x8*)(plane + r * 32 + ((quad ^ ((r >> 1) & 3)) << 3));
}

#define WAITVM4() asm volatile("s_waitcnt vmcnt(4)" ::: "memory")
#define WAITVM0() asm volatile("s_waitcnt vmcnt(0)" ::: "memory")

template <int EPI>
__global__ __launch_bounds__(512) void gemm256(
    const ushort* __restrict__ A, const ushort* __restrict__ Bt,
    const float* __restrict__ bias, void* __restrict__ Cv,
    const float* __restrict__ resid, int M, int N, int K) {
  __shared__ __align__(16) ushort lds[2][2][2][2][4096];  // [buf][A/B][half][kh][128*32]
  const int t = threadIdx.x;
  const int lane = t & 63, wave = t >> 6;
  const int wm = wave >> 2;            // A half this wave consumes
  const int wn = wave & 3;
  const int bh = wn >> 1;              // B half this wave consumes
  const int r15 = lane & 15, quad = lane >> 4;
  const size_t row0 = (size_t)blockIdx.y * 256;
  const size_t col0 = (size_t)blockIdx.x * 256;

  // stage-group indices: 4 waves per A-half (w&3), 4 waves per B-half
  const int gwA = wave & 3;
  const int gwB = ((wave >> 1) & 2) | (wave & 1);

  // per-lane pre-swizzled global source pointers (k0/kh added at issue time)
  const ushort *gA0, *gA1, *gB0, *gB1;
  {
    int p0 = gwA * 128 + lane;                 // chunks (gwA*2+0)*64+lane
    int p1 = p0 + 64;
    int ra0 = p0 >> 2, sa0 = (p0 & 3) ^ ((p0 >> 3) & 3);
    int ra1 = p1 >> 2, sa1 = (p1 & 3) ^ ((p1 >> 3) & 3);
    gA0 = A + (row0 + wm * 128 + ra0) * K + sa0 * 8;
    gA1 = A + (row0 + wm * 128 + ra1) * K + sa1 * 8;
    int q0 = gwB * 128 + lane;
    int q1 = q0 + 64;
    int rb0 = q0 >> 2, sb0 = (q0 & 3) ^ ((q0 >> 3) & 3);
    int rb1 = q1 >> 2, sb1 = (q1 & 3) ^ ((q1 >> 3) & 3);
    gB0 = Bt + (col0 + bh * 128 + rb0) * K + sb0 * 8;
    gB1 = Bt + (col0 + bh * 128 + rb1) * K + sb1 * 8;
  }
  const int ldsA0 = gwA * 1024, ldsA1 = gwA * 1024 + 512;   // ushort offsets
  const int ldsB0 = gwB * 1024, ldsB1 = gwB * 1024 + 512;

#define STAGE_A(nb_, skh_, kof_)                                        \
  do {                                                                  \
    g2lds16(gA0 + (kof_) + (skh_) * 32, &lds[nb_][0][wm][skh_][ldsA0]); \
    g2lds16(gA1 + (kof_) + (skh_) * 32, &lds[nb_][0][wm][skh_][ldsA1]); \
  } while (0)
#define STAGE_B(nb_, skh_, kof_)                                        \
  do {                                                                  \
    g2lds16(gB0 + (kof_) + (skh_) * 32, &lds[nb_][1][bh][skh_][ldsB0]); \
    g2lds16(gB1 + (kof_) + (skh_) * 32, &lds[nb_][1][bh][skh_][ldsB1]); \
  } while (0)

  f32x4 acc[8][4] = {};
  const int NT = K >> 6;

  // prologue: stage tile 0 into buf 0 (order A0,B0,A1,B1 — vmcnt counts rely on it)
  STAGE_A(0, 0, 0);
  STAGE_B(0, 0, 0);
  STAGE_A(0, 1, 0);
  STAGE_B(0, 1, 0);
  WAITVM4();                      // A-kh0 + B-kh0 resident
  __builtin_amdgcn_s_barrier();

  for (int tt = 0; tt < NT; ++tt) {
    const int cb = tt & 1, nb = cb ^ 1;
    const int kn = (tt + 1) << 6;
    const bool pf = (tt + 1 < NT);
    const ushort* pA0 = &lds[cb][0][wm][0][0];
    const ushort* pB0 = &lds[cb][1][bh][0][0];
    const ushort* pA1 = &lds[cb][0][wm][1][0];
    const ushort* pB1 = &lds[cb][1][bh][1][0];
    bf16x8 af[4], bfr[4];

    // ---- phase 0: kh=0, i 0-3 ----
#pragma unroll
    for (int j = 0; j < 4; ++j) bfr[j] = rdfrag(pB0, (wn & 1) * 64 + j * 16 + r15, quad);
#pragma unroll
    for (int i = 0; i < 4; ++i) af[i] = rdfrag(pA0, i * 16 + r15, quad);
    if (pf) STAGE_A(nb, 0, kn);
    __builtin_amdgcn_s_barrier();
    __builtin_amdgcn_s_setprio(1);
    mfma_blk<0>(acc, af, bfr);
    __builtin_amdgcn_s_setprio(0);
    __builtin_amdgcn_s_barrier();

    // ---- phase 1: kh=0, i 4-7 ----
#pragma unroll
    for (int i = 0; i < 4; ++i) af[i] = rdfrag(pA0, 64 + i * 16 + r15, quad);
    if (pf) STAGE_B(nb, 0, kn);
    __builtin_amdgcn_s_barrier();
    __builtin_amdgcn_s_setprio(1);
    mfma_blk<4>(acc, af, bfr);
    __builtin_amdgcn_s_setprio(0);
    if (tt == NT - 1) { WAITVM0(); } else { WAITVM4(); }   // kh1 strips resident
    __builtin_amdgcn_s_barrier();

    // ---- phase 2: kh=1, i 0-3 ----
#pragma unroll
    for (int j = 0; j < 4; ++j) bfr[j] = rdfrag(pB1, (wn & 1) * 64 + j * 16 + r15, quad);
#pragma unroll
    for (int i = 0; i < 4; ++i) af[i] = rdfrag(pA1, i * 16 + r15, quad);
    if (pf) STAGE_A(nb, 1, kn);
    __builtin_amdgcn_s_barrier();
    __builtin_amdgcn_s_setprio(1);
    mfma_blk<0>(acc, af, bfr);
    __builtin_amdgcn_s_setprio(0);
    __builtin_amdgcn_s_barrier();

    // ---- phase 3: kh=1, i 4-7 ----
#pragma unroll
    for (int i = 0; i < 4; ++i) af[i] = rdfrag(pA1, 64 + i * 16 + r15, quad);
    if (pf) STAGE_B(nb, 1, kn);
    __builtin_amdgcn_s_barrier();
    __builtin_amdgcn_s_setprio(1);
    mfma_blk<4>(acc, af, bfr);
    __builtin_amdgcn_s_setprio(0);
    if (pf) WAITVM4();            // next tile's kh0 strips resident
    __builtin_amdgcn_s_barrier();
  }

  // epilogue
  int mbase = (int)row0 + wm * 128;
  int nbase = (int)col0 + wn * 64;
#pragma unroll
  for (int j = 0; j < 4; ++j) {
    int col = nbase + j * 16 + r15;
    float bb = bias[col];
#pragma unroll
    for (int i = 0; i < 8; ++i) {
#pragma unroll
      for (int ii = 0; ii < 4; ++ii) {
        int row = mbase + i * 16 + quad * 4 + ii;
        size_t idx = (size_t)row * N + col;
        float v = acc[i][j][ii] + bb;
        if constexpr (EPI == 0) {
          ((ushort*)Cv)[idx] = f2b(v);
        } else if constexpr (EPI == 1) {
          float gl = 0.5f * v * (1.0f + erff(v * 0.70710678118f));
          ((ushort*)Cv)[idx] = f2b(gl);
        } else {
          ((float*)Cv)[idx] = v + resid[idx];
        }
      }
    }
  }
#undef STAGE_A
#undef STAGE_B
}

// ---------------------------------------------------------------------------
// MFMA attention.  One block (4 waves) per (b,h).
// scores = (Q@K^T)*0.125 + T[q, q-k],  T = Q@P^T  (P = pos_bf, rows d=q-k).
// ---------------------------------------------------------------------------
#define PW_STRIDE 228   // elems per row; 456B: 8B-aligned (b64 reads), ~4-way banks
__global__ __launch_bounds__(256) void attn_kernel(
    const ushort* __restrict__ qkv, const ushort* __restrict__ pos_bf,
    ushort* __restrict__ ctx) {
  int bh = blockIdx.x;
  int b = bh >> 4, h = bh & 15;
  __shared__ ushort Vt[64][PW_STRIDE];       // V^T: Vt[d][k]
  __shared__ ushort Pw[4][16][PW_STRIDE];    // per-wave: T strip, then exp(S)
  int t = threadIdx.x, lane = t & 63, wave = t >> 6;
  int r15 = lane & 15, quad = lane >> 4;
  const size_t base = ((size_t)b * S_LEN) * 3072 + (size_t)h * 64;

  // zero Vt pad cols 200..227
  for (int i = t; i < 64 * 28; i += 256) Vt[i / 28][200 + (i % 28)] = 0;
  // stage V transposed
  for (int i = t; i < 800; i += 256) {
    int kp = i >> 3, d0 = (i & 7) * 8;
    int k = kp * 2;
    union { uint4 v; ushort u[8]; } r0, r1;
    r0.v = *(const uint4*)&qkv[base + (size_t)k * 3072 + 2048 + d0];
    r1.v = *(const uint4*)&qkv[base + (size_t)(k + 1) * 3072 + 2048 + d0];
#pragma unroll
    for (int j = 0; j < 8; ++j) {
      ushort2 w2; w2.x = r0.u[j]; w2.y = r1.u[j];
      *(ushort2*)&Vt[d0 + j][k] = w2;
    }
  }
  __syncthreads();

  for (int qt = wave; qt < 13; qt += 4) {
    int q0 = qt * 16;
    int qrow = q0 + r15; if (qrow > 199) qrow = 199;
    const ushort* qp = qkv + base + (size_t)qrow * 3072;
    bf16x8 aq0 = ld_g16(qp + quad * 8);
    bf16x8 aq1 = ld_g16(qp + 32 + quad * 8);
    ushort* pw = &Pw[wave][0][0];

    // ---- Phase 1: T strip = Q @ P^T ----
#pragma unroll
    for (int dt = 0; dt < 13; ++dt) {
      if (dt > qt) continue;
      int prow = dt * 16 + r15; if (prow > 199) prow = 199;
      const ushort* pp = pos_bf + (size_t)prow * 64;
      bf16x8 p0 = ld_g16(pp + quad * 8);
      bf16x8 p1 = ld_g16(pp + 32 + quad * 8);
      f32x4 tt = {};
      tt = __builtin_amdgcn_mfma_f32_16x16x32_bf16(aq0, p0, tt, 0, 0, 0);
      tt = __builtin_amdgcn_mfma_f32_16x16x32_bf16(aq1, p1, tt, 0, 0, 0);
#pragma unroll
      for (int ii = 0; ii < 4; ++ii)
        pw[(quad * 4 + ii) * PW_STRIDE + dt * 16 + r15] = f2b(tt[ii]);
    }

    // ---- Phase 2: scores ----
    f32x4 sreg[13];
    float rowmax[4] = {-3.0e38f, -3.0e38f, -3.0e38f, -3.0e38f};
#pragma unroll
    for (int kt = 0; kt < 13; ++kt) {
      if (kt > qt) continue;
      int krow = kt * 16 + r15; if (krow > 199) krow = 199;
      const ushort* kp = qkv + base + (size_t)krow * 3072 + 1024;
      bf16x8 k0 = ld_g16(kp + quad * 8);
      bf16x8 k1 = ld_g16(kp + 32 + quad * 8);
      f32x4 s = {};
      s = __builtin_amdgcn_mfma_f32_16x16x32_bf16(aq0, k0, s, 0, 0, 0);
      s = __builtin_amdgcn_mfma_f32_16x16x32_bf16(aq1, k1, s, 0, 0, 0);
      int k = kt * 16 + r15;
#pragma unroll
      for (int ii = 0; ii < 4; ++ii) {
        int q = q0 + quad * 4 + ii;
        float v;
        if (k <= q) {
          v = s[ii] * 0.125f + b2f(pw[(quad * 4 + ii) * PW_STRIDE + (q - k)]);
        } else {
          v = -1.0e30f;
        }
        s[ii] = v;
        rowmax[ii] = fmaxf(rowmax[ii], v);
      }
      sreg[kt] = s;
    }
#pragma unroll
    for (int off = 8; off; off >>= 1)
#pragma unroll
      for (int ii = 0; ii < 4; ++ii)
        rowmax[ii] = fmaxf(rowmax[ii], __shfl_xor(rowmax[ii], off));

    float rsum[4] = {0.f, 0.f, 0.f, 0.f};
#pragma unroll
    for (int kt = 0; kt < 13; ++kt) {
      if (kt > qt) continue;
#pragma unroll
      for (int ii = 0; ii < 4; ++ii) {
        float e = __expf(sreg[kt][ii] - rowmax[ii]);
        rsum[ii] += e;
        pw[(quad * 4 + ii) * PW_STRIDE + kt * 16 + r15] = f2b(e);
      }
    }
    if ((qt & 1) == 0) {
#pragma unroll
      for (int ii = 0; ii < 4; ++ii)
        pw[(quad * 4 + ii) * PW_STRIDE + (qt + 1) * 16 + r15] = 0;
    }
#pragma unroll
    for (int off = 8; off; off >>= 1)
#pragma unroll
      for (int ii = 0; ii < 4; ++ii)
        rsum[ii] += __shfl_xor(rsum[ii], off);
    float rinv[4];
#pragma unroll
    for (int ii = 0; ii < 4; ++ii) rinv[ii] = 1.0f / rsum[ii];

    // ---- Phase 3: ctx = exp(S) @ V ----
    int nk = (q0 + 15) / 32 + 1;
    f32x4 acc[4] = {};
#pragma unroll
    for (int k32 = 0; k32 < 7; ++k32) {
      if (k32 >= nk) continue;
      bf16x8 ap = ld_lds8x2(&pw[r15 * PW_STRIDE + k32 * 32 + quad * 8]);
#pragma unroll
      for (int n = 0; n < 4; ++n) {
        bf16x8 bv = ld_lds8x2(&Vt[n * 16 + r15][k32 * 32 + quad * 8]);
        acc[n] = __builtin_amdgcn_mfma_f32_16x16x32_bf16(ap, bv, acc[n], 0, 0, 0);
      }
    }
#pragma unroll
    for (int n = 0; n < 4; ++n)
#pragma unroll
      for (int ii = 0; ii < 4; ++ii) {
        int q = q0 + quad * 4 + ii;
        if (q < S_LEN)
          ctx[((size_t)(b * S_LEN + q)) * H_DIM + h * 64 + n * 16 + r15] =
              f2b(acc[n][ii] * rinv[ii]);
      }
  }
}

// ---------------------------------------------------------------------------
// Launcher.  Workspace layout (aliased; peak ~124 MB):
//   [weights bf16^T: 25.2 MB][pos_bf 25.6KB][qkv 78.6 MB -> h2+gelu chunk]
//   [hbf 26.2 MB -> ctx]          res2 lives in d_out (fp32, 52.4 MB).
// ---------------------------------------------------------------------------
extern "C" void kernel_launch(void* const* d_in, const int* in_sizes, int n_in,
                              void* d_out, int out_size, void* d_ws, size_t ws_size,
                              hipStream_t stream) {
  (void)in_sizes; (void)n_in; (void)out_size; (void)ws_size;
  const float* x    = (const float*)d_in[0];
  const float* timev= (const float*)d_in[1];
  const float* wq   = (const float*)d_in[2];
  const float* bq   = (const float*)d_in[3];
  const float* wk   = (const float*)d_in[4];
  const float* bk   = (const float*)d_in[5];
  const float* wv   = (const float*)d_in[6];
  const float* bv   = (const float*)d_in[7];
  const float* wo   = (const float*)d_in[8];
  const float* bo   = (const float*)d_in[9];
  const float* wt   = (const float*)d_in[10];
  const float* bt   = (const float*)d_in[11];
  const float* pos  = (const float*)d_in[12];
  const float* g1   = (const float*)d_in[13];
  const float* be1  = (const float*)d_in[14];
  const float* g2   = (const float*)d_in[15];
  const float* be2  = (const float*)d_in[16];
  const float* w1   = (const float*)d_in[17];
  const float* bf1  = (const float*)d_in[18];
  const float* w2   = (const float*)d_in[19];
  const float* bf2  = (const float*)d_in[20];

  char* ws = (char*)d_ws;
  ushort* wqkv_t = (ushort*)ws;   ws += (size_t)3072 * 1024 * 2;   //  6.29 MB
  ushort* wo_t   = (ushort*)ws;   ws += (size_t)1024 * 1024 * 2;   //  2.10 MB
  ushort* w1_t   = (ushort*)ws;   ws += (size_t)4096 * 1024 * 2;   //  8.39 MB
  ushort* w2_t   = (ushort*)ws;   ws += (size_t)1024 * 4096 * 2;   //  8.39 MB
  float*  bqkv   = (float*)ws;    ws += (size_t)16384;             //  16 KB
  ushort* pos_bf = (ushort*)ws;   ws += (size_t)200 * 64 * 2;      //  25.6 KB
  // region R1: qkv during attention; afterwards h2 + gelu chunk
  char* r1 = ws;                  ws += (size_t)NROWS * 3072 * 2;  // 78.64 MB
  ushort* qkv  = (ushort*)r1;
  ushort* h2   = (ushort*)r1;                                      // 26.21 MB
  ushort* gbuf = (ushort*)(r1 + (size_t)NROWS * H_DIM * 2);        // 52.43 MB
  // region R2: hbf, then ctx
  char* r2 = ws;                  ws += (size_t)NROWS * 1024 * 2;  // 26.21 MB
  ushort* hbf = (ushort*)r2;
  ushort* ctx = (ushort*)r2;
  float* res2 = (float*)d_out;

  dim3 tb(32, 8);
  transpose_to_bf16<<<dim3(32, 32), tb, 0, stream>>>(wq, wqkv_t,                 1024, 1024);
  transpose_to_bf16<<<dim3(32, 32), tb, 0, stream>>>(wk, wqkv_t + 1024 * 1024,   1024, 1024);
  transpose_to_bf16<<<dim3(32, 32), tb, 0, stream>>>(wv, wqkv_t + 2048 * 1024,   1024, 1024);
  transpose_to_bf16<<<dim3(32, 32), tb, 0, stream>>>(wo, wo_t,                   1024, 1024);
  transpose_to_bf16<<<dim3(128, 32), tb, 0, stream>>>(w1, w1_t,                  1024, 4096);
  transpose_to_bf16<<<dim3(32, 128), tb, 0, stream>>>(w2, w2_t,                  4096, 1024);
  concat_bias<<<12, 256, 0, stream>>>(bq, bk, bv, bqkv);
  pos_to_bf16<<<50, 256, 0, stream>>>(pos, pos_bf);

  // LN1 + time embed -> hbf (bf16)
  ln_kernel<1><<<NROWS, 256, 0, stream>>>(x, g1, be1, timev, wt, bt, hbf);

  // fused QKV GEMM: [12800,1024] x [3072,1024]^T -> qkv bf16   (256^2 8-phase)
  gemm256<0><<<dim3(12, 50), 512, 0, stream>>>(hbf, wqkv_t, bqkv, qkv, nullptr,
                                               NROWS, 3072, 1024);
  // MFMA attention: qkv -> ctx (overwrites hbf region; hbf is dead now)
  attn_kernel<<<B_SZ * NHEAD, 256, 0, stream>>>(qkv, pos_bf, ctx);

  // out = ctx @ wo + bo + x   (fp32, into d_out as res2)
  gemm256<2><<<dim3(4, 50), 512, 0, stream>>>(ctx, wo_t, bo, res2, x,
                                              NROWS, 1024, 1024);
  // LN2 -> h2 (bf16, overwrites qkv region; qkv is dead now)
  ln_kernel<0><<<NROWS, 256, 0, stream>>>(res2, g2, be2, nullptr, nullptr, nullptr, h2);

  // FF in 2 row-chunks of 6400 (gelu buffer fits in the freed qkv region)
  for (int c = 0; c < 2; ++c) {
    size_t ro = (size_t)c * 6400;
    gemm256<1><<<dim3(16, 25), 512, 0, stream>>>(h2 + ro * 1024, w1_t, bf1, gbuf, nullptr,
                                                 6400, 4096, 1024);
    gemm_bt<2><<<dim3(8, 50), 256, 0, stream>>>(gbuf, w2_t, bf2, (float*)d_out + ro * 1024,
                                                res2 + ro * 1024, 6400, 1024, 4096);
  }
}

// Round 2
// 802.039 us; speedup vs baseline: 1.0147x; 1.0147x over previous
//
#include <hip/hip_runtime.h>

// Problem constants
#define B_SZ   64
#define S_LEN  200
#define H_DIM  1024
#define NHEAD  16
#define HDIM   64
#define FF_DIM 4096
#define NROWS  (B_SZ * S_LEN)   // 12800

typedef __bf16 bf16x8 __attribute__((ext_vector_type(8)));
typedef float  f32x4  __attribute__((ext_vector_type(4)));

#define GLOBAL_AS __attribute__((address_space(1)))
#define LDS_AS    __attribute__((address_space(3)))

__device__ __forceinline__ void g2lds16(const void* g, void* l) {
  __builtin_amdgcn_global_load_lds((const GLOBAL_AS void*)g, (LDS_AS void*)l, 16, 0, 0);
}

__device__ __forceinline__ float b2f(ushort u) {
  return __uint_as_float(((unsigned int)u) << 16);
}
__device__ __forceinline__ ushort f2b(float f) {
  unsigned int u = __float_as_uint(f);
  u += 0x7fffu + ((u >> 16) & 1u);   // RNE
  return (ushort)(u >> 16);
}
__device__ __forceinline__ bf16x8 ld_g16(const ushort* p) {   // 16B global load
  union { uint4 u; bf16x8 v; } r; r.u = *(const uint4*)p; return r.v;
}
__device__ __forceinline__ bf16x8 ld_lds8x2(const ushort* p) { // 2x ds_read_b64
  union { uint2 u[2]; bf16x8 v; } r;
  r.u[0] = *(const uint2*)p;
  r.u[1] = *(const uint2*)(p + 4);
  return r.v;
}

// ---------------------------------------------------------------------------
// Transpose fp32 [K,N] -> bf16 [N,K]
// ---------------------------------------------------------------------------
__global__ __launch_bounds__(256) void transpose_to_bf16(
    const float* __restrict__ w, ushort* __restrict__ wt, int K, int N) {
  __shared__ float tile[32][33];
  int nb = blockIdx.x * 32, kb = blockIdx.y * 32;
  int tx = threadIdx.x, ty = threadIdx.y;  // 32 x 8
#pragma unroll
  for (int i = 0; i < 4; ++i) {
    int k = kb + ty + i * 8;
    tile[ty + i * 8][tx] = w[(size_t)k * N + nb + tx];
  }
  __syncthreads();
#pragma unroll
  for (int i = 0; i < 4; ++i) {
    int n = nb + ty + i * 8;
    wt[(size_t)n * K + kb + tx] = f2b(tile[tx][ty + i * 8]);
  }
}

// ---------------------------------------------------------------------------
// Concat 3 biases of 1024 into one 3072 vector
// ---------------------------------------------------------------------------
__global__ void concat_bias(const float* __restrict__ bq, const float* __restrict__ bk,
                            const float* __restrict__ bv, float* __restrict__ o) {
  int i = blockIdx.x * 256 + threadIdx.x;
  if (i < 1024) o[i] = bq[i];
  else if (i < 2048) o[i] = bk[i - 1024];
  else if (i < 3072) o[i] = bv[i - 2048];
}

// ---------------------------------------------------------------------------
// pos rows 199..398 (the causal-reachable range) -> bf16 [200][64]
// ---------------------------------------------------------------------------
__global__ void pos_to_bf16(const float* __restrict__ pos, ushort* __restrict__ pb) {
  int i = blockIdx.x * 256 + threadIdx.x;   // 50 blocks x 256 = 12800
  pb[i] = f2b(pos[(size_t)199 * 64 + i]);
}

// ---------------------------------------------------------------------------
// LayerNorm (fp32 in) -> bf16 out.  HAS_TIME: += time[r]*wt[c] + bt[c]
// ---------------------------------------------------------------------------
template <int HAS_TIME>
__global__ __launch_bounds__(256) void ln_kernel(
    const float* __restrict__ x, const float* __restrict__ g, const float* __restrict__ be,
    const float* __restrict__ tv, const float* __restrict__ wt, const float* __restrict__ bt,
    ushort* __restrict__ out) {
  int r = blockIdx.x, t = threadIdx.x;
  const float4* xr = (const float4*)(x + (size_t)r * H_DIM);
  float4 xv = xr[t];
  float s  = xv.x + xv.y + xv.z + xv.w;
  float s2 = xv.x * xv.x + xv.y * xv.y + xv.z * xv.z + xv.w * xv.w;
#pragma unroll
  for (int off = 32; off; off >>= 1) {
    s  += __shfl_xor(s, off);
    s2 += __shfl_xor(s2, off);
  }
  __shared__ float red[8];
  int lane = t & 63, wid = t >> 6;
  if (lane == 0) { red[wid] = s; red[4 + wid] = s2; }
  __syncthreads();
  float S  = red[0] + red[1] + red[2] + red[3];
  float S2 = red[4] + red[5] + red[6] + red[7];
  float m    = S * (1.0f / H_DIM);
  float var  = S2 * (1.0f / H_DIM) - m * m;
  float rstd = rsqrtf(var + 1e-5f);
  float tval = HAS_TIME ? tv[r] : 0.0f;
  float4 gv = ((const float4*)g)[t];
  float4 bv = ((const float4*)be)[t];
  float v0 = (xv.x - m) * rstd * gv.x + bv.x;
  float v1 = (xv.y - m) * rstd * gv.y + bv.y;
  float v2 = (xv.z - m) * rstd * gv.z + bv.z;
  float v3 = (xv.w - m) * rstd * gv.w + bv.w;
  if (HAS_TIME) {
    float4 wv = ((const float4*)wt)[t];
    float4 btv = ((const float4*)bt)[t];
    v0 += tval * wv.x + btv.x;
    v1 += tval * wv.y + btv.y;
    v2 += tval * wv.z + btv.z;
    v3 += tval * wv.w + btv.w;
  }
  ushort4 o;
  o.x = f2b(v0); o.y = f2b(v1); o.z = f2b(v2); o.w = f2b(v3);
  ((ushort4*)(out + (size_t)r * H_DIM))[t] = o;
}

// ---------------------------------------------------------------------------
// Old 128x128 GEMM (kept for FF2 where chunked-M makes 256^2 grids too small)
// Now with XCD-aware block swizzle (grid blocks % 8 == 0 at all call sites).
// ---------------------------------------------------------------------------
template <int EPI>
__global__ __launch_bounds__(256) void gemm_bt(
    const ushort* __restrict__ A, const ushort* __restrict__ Bt,
    const float* __restrict__ bias, void* __restrict__ Cv,
    const float* __restrict__ resid, int M, int N, int K) {
  __shared__ __align__(16) ushort As[2 * 128 * 32];   // [kh][row][32]
  __shared__ __align__(16) ushort Bs[2 * 128 * 32];
  int t = threadIdx.x;
  int lane = t & 63, wave = t >> 6;
  int wm = wave >> 1, wn = wave & 1;
  int r15 = lane & 15, quad = lane >> 4;
  // XCD swizzle (T1): consecutive swz ids share A-panels on one XCD L2
  int nwg = gridDim.x * gridDim.y;
  int bid = blockIdx.y * gridDim.x + blockIdx.x;
  int swz = (bid & 7) * (nwg >> 3) + (bid >> 3);
  int bx = swz % gridDim.x, by = swz / gridDim.x;
  size_t row0 = (size_t)by * 128;
  size_t col0 = (size_t)bx * 128;

  int srow = (lane >> 2), scol = (lane & 3) * 8;
  const ushort* ga0 = A  + (row0 + wave * 32 +      srow) * K + scol;
  const ushort* ga1 = A  + (row0 + wave * 32 + 16 + srow) * K + scol;
  const ushort* gb0 = Bt + (col0 + wave * 32 +      srow) * K + scol;
  const ushort* gb1 = Bt + (col0 + wave * 32 + 16 + srow) * K + scol;
  ushort* la0 = As + (wave * 32) * 32;
  ushort* la1 = As + (wave * 32 + 16) * 32;
  ushort* lb0 = Bs + (wave * 32) * 32;
  ushort* lb1 = Bs + (wave * 32 + 16) * 32;

  f32x4 acc[4][4] = {};

  for (int k0 = 0; k0 < K; k0 += 64) {
#pragma unroll
    for (int kh = 0; kh < 2; ++kh) {
      int go = k0 + kh * 32, lo = kh * 4096;
      g2lds16(ga0 + go, la0 + lo);
      g2lds16(ga1 + go, la1 + lo);
      g2lds16(gb0 + go, lb0 + lo);
      g2lds16(gb1 + go, lb1 + lo);
    }
    __syncthreads();
#pragma unroll
    for (int kh = 0; kh < 2; ++kh) {
      bf16x8 af[4], bfr[4];
#pragma unroll
      for (int i = 0; i < 4; ++i)
        af[i] = *(const bf16x8*)&As[kh * 4096 + (wm * 64 + i * 16 + r15) * 32 + quad * 8];
#pragma unroll
      for (int j = 0; j < 4; ++j)
        bfr[j] = *(const bf16x8*)&Bs[kh * 4096 + (wn * 64 + j * 16 + r15) * 32 + quad * 8];
#pragma unroll
      for (int i = 0; i < 4; ++i)
#pragma unroll
        for (int j = 0; j < 4; ++j)
          acc[i][j] = __builtin_amdgcn_mfma_f32_16x16x32_bf16(af[i], bfr[j], acc[i][j], 0, 0, 0);
    }
    __syncthreads();
  }

  int mbase = (int)row0 + wm * 64;
  int nbase = (int)col0 + wn * 64;
#pragma unroll
  for (int i = 0; i < 4; ++i) {
#pragma unroll
    for (int j = 0; j < 4; ++j) {
      int col = nbase + j * 16 + r15;
      float bb = bias[col];
#pragma unroll
      for (int ii = 0; ii < 4; ++ii) {
        int row = mbase + i * 16 + quad * 4 + ii;
        size_t idx = (size_t)row * N + col;
        float v = acc[i][j][ii] + bb;
        if constexpr (EPI == 0) {
          ((ushort*)Cv)[idx] = f2b(v);
        } else if constexpr (EPI == 1) {
          float gl = 0.5f * v * (1.0f + erff(v * 0.70710678118f));
          ((ushort*)Cv)[idx] = f2b(gl);
        } else {
          ((float*)Cv)[idx] = v + resid[idx];
        }
      }
    }
  }
}

// ---------------------------------------------------------------------------
// 256x256 8-phase GEMM, m201-faithful schedule (T1+T2+T3+T4+T5).
//   512 thr = 8 waves (2M x 4N), per-wave C = 128x64.  BK=64, 2 K-tiles/iter.
//   LDS 128 KiB: [buf][A/B][half][kh] planes of [128 rows][32 k] bf16 (8 KB).
//   One stage op (2 x global_load_lds w=16 per thread) per phase; uniform
//   s_waitcnt vmcnt(8) at ends of phases 1/3/5/7 only -> 8-12 loads in
//   flight, 6-phase issue-to-consume distance.  Tail iteration peeled with
//   drain counts 8/4/0.  16 MFMA per phase under setprio(1).
//   Chunk swizzle slot ^= (row>>1)&3 on global source + ds_read (rule #21);
//   verified conflict-free (round-1 SQ_LDS_BANK_CONFLICT == 0).
//   Requires M%256==0, N%256==0, K%128==0, grid blocks %8==0.
// ---------------------------------------------------------------------------
template <int IB>
__device__ __forceinline__ void mfma_blk(f32x4 (&acc)[8][4],
                                         const bf16x8 (&af)[4], const bf16x8 (&bfr)[4]) {
#pragma unroll
  for (int i = 0; i < 4; ++i)
#pragma unroll
    for (int j = 0; j < 4; ++j)
      acc[IB + i][j] =
          __builtin_amdgcn_mfma_f32_16x16x32_bf16(af[i], bfr[j], acc[IB + i][j], 0, 0, 0);
}

__device__ __forceinline__ bf16x8 rdfrag(const ushort* plane, int r, int quad) {
  // logical (row r, 16B-slot quad) -> physical slot quad ^ ((r>>1)&3)
  return *(const bf16x8*)(plane + r * 32 + ((quad ^ ((r >> 1) & 3)) << 3));
}

__device__ __forceinline__ void read_q0(bf16x8 (&af)[4], bf16x8 (&bfr)[4],
                                        const ushort* pA, const ushort* pB,
                                        int wn1, int r15, int quad) {
#pragma unroll
  for (int j = 0; j < 4; ++j) bfr[j] = rdfrag(pB, wn1 * 64 + j * 16 + r15, quad);
#pragma unroll
  for (int i = 0; i < 4; ++i) af[i] = rdfrag(pA, i * 16 + r15, quad);
}
__device__ __forceinline__ void read_q1(bf16x8 (&af)[4], const ushort* pA,
                                        int r15, int quad) {
#pragma unroll
  for (int i = 0; i < 4; ++i) af[i] = rdfrag(pA, 64 + i * 16 + r15, quad);
}

#define VMW8() asm volatile("s_waitcnt vmcnt(8)" ::: "memory")
#define VMW4() asm volatile("s_waitcnt vmcnt(4)" ::: "memory")
#define VMW0() asm volatile("s_waitcnt vmcnt(0)" ::: "memory")
#define BARX() __builtin_amdgcn_s_barrier()
#define PRIO1() __builtin_amdgcn_s_setprio(1)
#define PRIO0() __builtin_amdgcn_s_setprio(0)

template <int EPI>
__global__ __launch_bounds__(512) void gemm256(
    const ushort* __restrict__ A, const ushort* __restrict__ Bt,
    const float* __restrict__ bias, void* __restrict__ Cv,
    const float* __restrict__ resid, int M, int N, int K) {
  __shared__ __align__(16) ushort lds[2][2][2][2][4096];  // [buf][A/B][half][kh][128*32]
  const int t = threadIdx.x;
  const int lane = t & 63, wave = t >> 6;
  const int wm = wave >> 2;            // A half this wave consumes
  const int wn = wave & 3;
  const int wn1 = wn & 1;
  const int bh = wn >> 1;              // B half this wave consumes
  const int r15 = lane & 15, quad = lane >> 4;
  // XCD swizzle (T1)
  int nwg = gridDim.x * gridDim.y;
  int bid = blockIdx.y * gridDim.x + blockIdx.x;
  int swz = (bid & 7) * (nwg >> 3) + (bid >> 3);
  int bx = swz % gridDim.x, by = swz / gridDim.x;
  const size_t row0 = (size_t)by * 256;
  const size_t col0 = (size_t)bx * 256;

  // stage-group indices: 4 waves per A-half, 4 waves per B-half
  const int gwA = wave & 3;
  const int gwB = ((wave >> 1) & 2) | (wave & 1);

  // per-lane pre-swizzled global source pointers (k offset added at issue)
  const ushort *gA0, *gA1, *gB0, *gB1;
  {
    int p0 = gwA * 128 + lane;
    int p1 = p0 + 64;
    int ra0 = p0 >> 2, sa0 = (p0 & 3) ^ ((p0 >> 3) & 3);
    int ra1 = p1 >> 2, sa1 = (p1 & 3) ^ ((p1 >> 3) & 3);
    gA0 = A + (row0 + wm * 128 + ra0) * K + sa0 * 8;
    gA1 = A + (row0 + wm * 128 + ra1) * K + sa1 * 8;
    int q0 = gwB * 128 + lane;
    int q1 = q0 + 64;
    int rb0 = q0 >> 2, sb0 = (q0 & 3) ^ ((q0 >> 3) & 3);
    int rb1 = q1 >> 2, sb1 = (q1 & 3) ^ ((q1 >> 3) & 3);
    gB0 = Bt + (col0 + bh * 128 + rb0) * K + sb0 * 8;
    gB1 = Bt + (col0 + bh * 128 + rb1) * K + sb1 * 8;
  }
  const int ldsA0 = gwA * 1024, ldsA1 = gwA * 1024 + 512;   // ushort offsets
  const int ldsB0 = gwB * 1024, ldsB1 = gwB * 1024 + 512;

#define STAGE_A(nb_, skh_, kof_)                                        \
  do {                                                                  \
    g2lds16(gA0 + (kof_) + (skh_) * 32, &lds[nb_][0][wm][skh_][ldsA0]); \
    g2lds16(gA1 + (kof_) + (skh_) * 32, &lds[nb_][0][wm][skh_][ldsA1]); \
  } while (0)
#define STAGE_B(nb_, skh_, kof_)                                        \
  do {                                                                  \
    g2lds16(gB0 + (kof_) + (skh_) * 32, &lds[nb_][1][bh][skh_][ldsB0]); \
    g2lds16(gB1 + (kof_) + (skh_) * 32, &lds[nb_][1][bh][skh_][ldsB1]); \
  } while (0)
#define PAP(b_, k_) (&lds[b_][0][wm][k_][0])
#define PBP(b_, k_) (&lds[b_][1][bh][k_][0])

  f32x4 acc[8][4] = {};

  // prologue: tile0 full + tile1 kh0 (6 stage ops = 12 loads/thread)
  STAGE_A(0, 0, 0);
  STAGE_B(0, 0, 0);
  STAGE_A(0, 1, 0);
  STAGE_B(0, 1, 0);
  STAGE_A(1, 0, 64);
  STAGE_B(1, 0, 64);
  VMW8();                       // tile0 kh0 (A,B) resident; 8 loads in flight
  BARX();

  // Iteration body: tiles a=2i (buf0) and b=2i+1 (buf1), ka_ = a*64.
  // Stages: P0:b.A1  P1:b.B1  P2:(a+2).A0  P3:(a+2).B0
  //         P4:(a+2).A1  P5:(a+2).B1  P6:(a+3).A0  P7:(a+3).B0
  // Waits (end of phase): P1:vm8  P3:vm8|vm4(last)  P5:vm8|vm0(last)
  //                       P7:vm8|none(last)
#define ITER_BODY(LAST_, ka_)                                                  \
  {                                                                            \
    bf16x8 af[4], bfr[4];                                                      \
    /* P0: buf0 kh0 Q0 */                                                      \
    read_q0(af, bfr, PAP(0, 0), PBP(0, 0), wn1, r15, quad);                    \
    STAGE_A(1, 1, (ka_) + 64);                                                 \
    BARX(); PRIO1(); mfma_blk<0>(acc, af, bfr); PRIO0(); BARX();               \
    /* P1: buf0 kh0 Q1 */                                                      \
    read_q1(af, PAP(0, 0), r15, quad);                                         \
    STAGE_B(1, 1, (ka_) + 64);                                                 \
    BARX(); PRIO1(); mfma_blk<4>(acc, af, bfr); PRIO0();                       \
    VMW8(); BARX();                                                            \
    /* P2: buf0 kh1 Q0 */                                                      \
    read_q0(af, bfr, PAP(0, 1), PBP(0, 1), wn1, r15, quad);                    \
    if (!(LAST_)) STAGE_A(0, 0, (ka_) + 128);                                  \
    BARX(); PRIO1(); mfma_blk<0>(acc, af, bfr); PRIO0(); BARX();               \
    /* P3: buf0 kh1 Q1 */                                                      \
    read_q1(af, PAP(0, 1), r15, quad);                                         \
    if (!(LAST_)) STAGE_B(0, 0, (ka_) + 128);                                  \
    BARX(); PRIO1(); mfma_blk<4>(acc, af, bfr); PRIO0();                       \
    if (LAST_) { VMW4(); } else { VMW8(); }                                    \
    BARX();                                                                    \
    /* P4: buf1 kh0 Q0 */                                                      \
    read_q0(af, bfr, PAP(1, 0), PBP(1, 0), wn1, r15, quad);                    \
    if (!(LAST_)) STAGE_A(0, 1, (ka_) + 128);                                  \
    BARX(); PRIO1(); mfma_blk<0>(acc, af, bfr); PRIO0(); BARX();               \
    /* P5: buf1 kh0 Q1 */                                                      \
    read_q1(af, PAP(1, 0), r15, quad);                                         \
    if (!(LAST_)) STAGE_B(0, 1, (ka_) + 128);                                  \
    BARX(); PRIO1(); mfma_blk<4>(acc, af, bfr); PRIO0();                       \
    if (LAST_) { VMW0(); } else { VMW8(); }                                    \
    BARX();                                                                    \
    /* P6: buf1 kh1 Q0 */                                                      \
    read_q0(af, bfr, PAP(1, 1), PBP(1, 1), wn1, r15, quad);                    \
    if (!(LAST_)) STAGE_A(1, 0, (ka_) + 192);                                  \
    BARX(); PRIO1(); mfma_blk<0>(acc, af, bfr); PRIO0(); BARX();               \
    /* P7: buf1 kh1 Q1 */                                                      \
    read_q1(af, PAP(1, 1), r15, quad);                                         \
    if (!(LAST_)) STAGE_B(1, 0, (ka_) + 192);                                  \
    BARX(); PRIO1(); mfma_blk<4>(acc, af, bfr); PRIO0();                       \
    if (!(LAST_)) { VMW8(); }                                                  \
    BARX();                                                                    \
  }

  const int NI = K >> 7;   // two 64-wide K-tiles per iteration
  for (int it = 0; it < NI - 1; ++it) {
    ITER_BODY(0, it << 7);
  }
  ITER_BODY(1, (NI - 1) << 7);
#undef ITER_BODY

  // epilogue
  int mbase = (int)row0 + wm * 128;
  int nbase = (int)col0 + wn * 64;
#pragma unroll
  for (int j = 0; j < 4; ++j) {
    int col = nbase + j * 16 + r15;
    float bb = bias[col];
#pragma unroll
    for (int i = 0; i < 8; ++i) {
#pragma unroll
      for (int ii = 0; ii < 4; ++ii) {
        int row = mbase + i * 16 + quad * 4 + ii;
        size_t idx = (size_t)row * N + col;
        float v = acc[i][j][ii] + bb;
        if constexpr (EPI == 0) {
          ((ushort*)Cv)[idx] = f2b(v);
        } else if constexpr (EPI == 1) {
          float gl = 0.5f * v * (1.0f + erff(v * 0.70710678118f));
          ((ushort*)Cv)[idx] = f2b(gl);
        } else {
          ((float*)Cv)[idx] = v + resid[idx];
        }
      }
    }
  }
#undef STAGE_A
#undef STAGE_B
#undef PAP
#undef PBP
}

// ---------------------------------------------------------------------------
// MFMA attention.  One block (4 waves) per (b,h).
// scores = (Q@K^T)*0.125 + T[q, q-k],  T = Q@P^T  (P = pos_bf, rows d=q-k).
// ---------------------------------------------------------------------------
#define PW_STRIDE 228   // elems per row; 456B: 8B-aligned (b64 reads), ~4-way banks
__global__ __launch_bounds__(256) void attn_kernel(
    const ushort* __restrict__ qkv, const ushort* __restrict__ pos_bf,
    ushort* __restrict__ ctx) {
  int bh = blockIdx.x;
  int b = bh >> 4, h = bh & 15;
  __shared__ ushort Vt[64][PW_STRIDE];       // V^T: Vt[d][k]
  __shared__ ushort Pw[4][16][PW_STRIDE];    // per-wave: T strip, then exp(S)
  int t = threadIdx.x, lane = t & 63, wave = t >> 6;
  int r15 = lane & 15, quad = lane >> 4;
  const size_t base = ((size_t)b * S_LEN) * 3072 + (size_t)h * 64;

  // zero Vt pad cols 200..227
  for (int i = t; i < 64 * 28; i += 256) Vt[i / 28][200 + (i % 28)] = 0;
  // stage V transposed
  for (int i = t; i < 800; i += 256) {
    int kp = i >> 3, d0 = (i & 7) * 8;
    int k = kp * 2;
    union { uint4 v; ushort u[8]; } r0, r1;
    r0.v = *(const uint4*)&qkv[base + (size_t)k * 3072 + 2048 + d0];
    r1.v = *(const uint4*)&qkv[base + (size_t)(k + 1) * 3072 + 2048 + d0];
#pragma unroll
    for (int j = 0; j < 8; ++j) {
      ushort2 w2; w2.x = r0.u[j]; w2.y = r1.u[j];
      *(ushort2*)&Vt[d0 + j][k] = w2;
    }
  }
  __syncthreads();

  for (int qt = wave; qt < 13; qt += 4) {
    int q0 = qt * 16;
    int qrow = q0 + r15; if (qrow > 199) qrow = 199;
    const ushort* qp = qkv + base + (size_t)qrow * 3072;
    bf16x8 aq0 = ld_g16(qp + quad * 8);
    bf16x8 aq1 = ld_g16(qp + 32 + quad * 8);
    ushort* pw = &Pw[wave][0][0];

    // ---- Phase 1: T strip = Q @ P^T ----
#pragma unroll
    for (int dt = 0; dt < 13; ++dt) {
      if (dt > qt) continue;
      int prow = dt * 16 + r15; if (prow > 199) prow = 199;
      const ushort* pp = pos_bf + (size_t)prow * 64;
      bf16x8 p0 = ld_g16(pp + quad * 8);
      bf16x8 p1 = ld_g16(pp + 32 + quad * 8);
      f32x4 tt = {};
      tt = __builtin_amdgcn_mfma_f32_16x16x32_bf16(aq0, p0, tt, 0, 0, 0);
      tt = __builtin_amdgcn_mfma_f32_16x16x32_bf16(aq1, p1, tt, 0, 0, 0);
#pragma unroll
      for (int ii = 0; ii < 4; ++ii)
        pw[(quad * 4 + ii) * PW_STRIDE + dt * 16 + r15] = f2b(tt[ii]);
    }

    // ---- Phase 2: scores ----
    f32x4 sreg[13];
    float rowmax[4] = {-3.0e38f, -3.0e38f, -3.0e38f, -3.0e38f};
#pragma unroll
    for (int kt = 0; kt < 13; ++kt) {
      if (kt > qt) continue;
      int krow = kt * 16 + r15; if (krow > 199) krow = 199;
      const ushort* kp = qkv + base + (size_t)krow * 3072 + 1024;
      bf16x8 k0 = ld_g16(kp + quad * 8);
      bf16x8 k1 = ld_g16(kp + 32 + quad * 8);
      f32x4 s = {};
      s = __builtin_amdgcn_mfma_f32_16x16x32_bf16(aq0, k0, s, 0, 0, 0);
      s = __builtin_amdgcn_mfma_f32_16x16x32_bf16(aq1, k1, s, 0, 0, 0);
      int k = kt * 16 + r15;
#pragma unroll
      for (int ii = 0; ii < 4; ++ii) {
        int q = q0 + quad * 4 + ii;
        float v;
        if (k <= q) {
          v = s[ii] * 0.125f + b2f(pw[(quad * 4 + ii) * PW_STRIDE + (q - k)]);
        } else {
          v = -1.0e30f;
        }
        s[ii] = v;
        rowmax[ii] = fmaxf(rowmax[ii], v);
      }
      sreg[kt] = s;
    }
#pragma unroll
    for (int off = 8; off; off >>= 1)
#pragma unroll
      for (int ii = 0; ii < 4; ++ii)
        rowmax[ii] = fmaxf(rowmax[ii], __shfl_xor(rowmax[ii], off));

    float rsum[4] = {0.f, 0.f, 0.f, 0.f};
#pragma unroll
    for (int kt = 0; kt < 13; ++kt) {
      if (kt > qt) continue;
#pragma unroll
      for (int ii = 0; ii < 4; ++ii) {
        float e = __expf(sreg[kt][ii] - rowmax[ii]);
        rsum[ii] += e;
        pw[(quad * 4 + ii) * PW_STRIDE + kt * 16 + r15] = f2b(e);
      }
    }
    if ((qt & 1) == 0) {
#pragma unroll
      for (int ii = 0; ii < 4; ++ii)
        pw[(quad * 4 + ii) * PW_STRIDE + (qt + 1) * 16 + r15] = 0;
    }
#pragma unroll
    for (int off = 8; off; off >>= 1)
#pragma unroll
      for (int ii = 0; ii < 4; ++ii)
        rsum[ii] += __shfl_xor(rsum[ii], off);
    float rinv[4];
#pragma unroll
    for (int ii = 0; ii < 4; ++ii) rinv[ii] = 1.0f / rsum[ii];

    // ---- Phase 3: ctx = exp(S) @ V ----
    int nk = (q0 + 15) / 32 + 1;
    f32x4 acc[4] = {};
#pragma unroll
    for (int k32 = 0; k32 < 7; ++k32) {
      if (k32 >= nk) continue;
      bf16x8 ap = ld_lds8x2(&pw[r15 * PW_STRIDE + k32 * 32 + quad * 8]);
#pragma unroll
      for (int n = 0; n < 4; ++n) {
        bf16x8 bv = ld_lds8x2(&Vt[n * 16 + r15][k32 * 32 + quad * 8]);
        acc[n] = __builtin_amdgcn_mfma_f32_16x16x32_bf16(ap, bv, acc[n], 0, 0, 0);
      }
    }
#pragma unroll
    for (int n = 0; n < 4; ++n)
#pragma unroll
      for (int ii = 0; ii < 4; ++ii) {
        int q = q0 + quad * 4 + ii;
        if (q < S_LEN)
          ctx[((size_t)(b * S_LEN + q)) * H_DIM + h * 64 + n * 16 + r15] =
              f2b(acc[n][ii] * rinv[ii]);
      }
  }
}

// ---------------------------------------------------------------------------
// Launcher.  Workspace layout (aliased; peak ~124 MB):
//   [weights bf16^T: 25.2 MB][pos_bf 25.6KB][qkv 78.6 MB -> h2+gelu chunk]
//   [hbf 26.2 MB -> ctx]          res2 lives in d_out (fp32, 52.4 MB).
// ---------------------------------------------------------------------------
extern "C" void kernel_launch(void* const* d_in, const int* in_sizes, int n_in,
                              void* d_out, int out_size, void* d_ws, size_t ws_size,
                              hipStream_t stream) {
  (void)in_sizes; (void)n_in; (void)out_size; (void)ws_size;
  const float* x    = (const float*)d_in[0];
  const float* timev= (const float*)d_in[1];
  const float* wq   = (const float*)d_in[2];
  const float* bq   = (const float*)d_in[3];
  const float* wk   = (const float*)d_in[4];
  const float* bk   = (const float*)d_in[5];
  const float* wv   = (const float*)d_in[6];
  const float* bv   = (const float*)d_in[7];
  const float* wo   = (const float*)d_in[8];
  const float* bo   = (const float*)d_in[9];
  const float* wt   = (const float*)d_in[10];
  const float* bt   = (const float*)d_in[11];
  const float* pos  = (const float*)d_in[12];
  const float* g1   = (const float*)d_in[13];
  const float* be1  = (const float*)d_in[14];
  const float* g2   = (const float*)d_in[15];
  const float* be2  = (const float*)d_in[16];
  const float* w1   = (const float*)d_in[17];
  const float* bf1  = (const float*)d_in[18];
  const float* w2   = (const float*)d_in[19];
  const float* bf2  = (const float*)d_in[20];

  char* ws = (char*)d_ws;
  ushort* wqkv_t = (ushort*)ws;   ws += (size_t)3072 * 1024 * 2;   //  6.29 MB
  ushort* wo_t   = (ushort*)ws;   ws += (size_t)1024 * 1024 * 2;   //  2.10 MB
  ushort* w1_t   = (ushort*)ws;   ws += (size_t)4096 * 1024 * 2;   //  8.39 MB
  ushort* w2_t   = (ushort*)ws;   ws += (size_t)1024 * 4096 * 2;   //  8.39 MB
  float*  bqkv   = (float*)ws;    ws += (size_t)16384;             //  16 KB
  ushort* pos_bf = (ushort*)ws;   ws += (size_t)200 * 64 * 2;      //  25.6 KB
  // region R1: qkv during attention; afterwards h2 + gelu chunk
  char* r1 = ws;                  ws += (size_t)NROWS * 3072 * 2;  // 78.64 MB
  ushort* qkv  = (ushort*)r1;
  ushort* h2   = (ushort*)r1;                                      // 26.21 MB
  ushort* gbuf = (ushort*)(r1 + (size_t)NROWS * H_DIM * 2);        // 52.43 MB
  // region R2: hbf, then ctx
  char* r2 = ws;                  ws += (size_t)NROWS * 1024 * 2;  // 26.21 MB
  ushort* hbf = (ushort*)r2;
  ushort* ctx = (ushort*)r2;
  float* res2 = (float*)d_out;

  dim3 tb(32, 8);
  transpose_to_bf16<<<dim3(32, 32), tb, 0, stream>>>(wq, wqkv_t,                 1024, 1024);
  transpose_to_bf16<<<dim3(32, 32), tb, 0, stream>>>(wk, wqkv_t + 1024 * 1024,   1024, 1024);
  transpose_to_bf16<<<dim3(32, 32), tb, 0, stream>>>(wv, wqkv_t + 2048 * 1024,   1024, 1024);
  transpose_to_bf16<<<dim3(32, 32), tb, 0, stream>>>(wo, wo_t,                   1024, 1024);
  transpose_to_bf16<<<dim3(128, 32), tb, 0, stream>>>(w1, w1_t,                  1024, 4096);
  transpose_to_bf16<<<dim3(32, 128), tb, 0, stream>>>(w2, w2_t,                  4096, 1024);
  concat_bias<<<12, 256, 0, stream>>>(bq, bk, bv, bqkv);
  pos_to_bf16<<<50, 256, 0, stream>>>(pos, pos_bf);

  // LN1 + time embed -> hbf (bf16)
  ln_kernel<1><<<NROWS, 256, 0, stream>>>(x, g1, be1, timev, wt, bt, hbf);

  // fused QKV GEMM: [12800,1024] x [3072,1024]^T -> qkv bf16   (256^2 8-phase)
  gemm256<0><<<dim3(12, 50), 512, 0, stream>>>(hbf, wqkv_t, bqkv, qkv, nullptr,
                                               NROWS, 3072, 1024);
  // MFMA attention: qkv -> ctx (overwrites hbf region; hbf is dead now)
  attn_kernel<<<B_SZ * NHEAD, 256, 0, stream>>>(qkv, pos_bf, ctx);

  // out = ctx @ wo + bo + x   (fp32, into d_out as res2)
  gemm256<2><<<dim3(4, 50), 512, 0, stream>>>(ctx, wo_t, bo, res2, x,
                                              NROWS, 1024, 1024);
  // LN2 -> h2 (bf16, overwrites qkv region; qkv is dead now)
  ln_kernel<0><<<NROWS, 256, 0, stream>>>(res2, g2, be2, nullptr, nullptr, nullptr, h2);

  // FF in 2 row-chunks of 6400 (gelu buffer fits in the freed qkv region)
  for (int c = 0; c < 2; ++c) {
    size_t ro = (size_t)c * 6400;
    gemm256<1><<<dim3(16, 25), 512, 0, stream>>>(h2 + ro * 1024, w1_t, bf1, gbuf, nullptr,
                                                 6400, 4096, 1024);
    gemm_bt<2><<<dim3(8, 50), 256, 0, stream>>>(gbuf, w2_t, bf2, (float*)d_out + ro * 1024,
                                                res2 + ro * 1024, 6400, 1024, 4096);
  }
}

// Round 3
// 773.863 us; speedup vs baseline: 1.0516x; 1.0364x over previous
//
#include <hip/hip_runtime.h>

// Problem constants
#define B_SZ   64
#define S_LEN  200
#define H_DIM  1024
#define NHEAD  16
#define HDIM   64
#define FF_DIM 4096
#define NROWS  (B_SZ * S_LEN)   // 12800

typedef __bf16 bf16x8 __attribute__((ext_vector_type(8)));
typedef float  f32x4  __attribute__((ext_vector_type(4)));

#define GLOBAL_AS __attribute__((address_space(1)))
#define LDS_AS    __attribute__((address_space(3)))

__device__ __forceinline__ void g2lds16(const void* g, void* l) {
  __builtin_amdgcn_global_load_lds((const GLOBAL_AS void*)g, (LDS_AS void*)l, 16, 0, 0);
}

__device__ __forceinline__ float b2f(ushort u) {
  return __uint_as_float(((unsigned int)u) << 16);
}
__device__ __forceinline__ ushort f2b(float f) {
  unsigned int u = __float_as_uint(f);
  u += 0x7fffu + ((u >> 16) & 1u);   // RNE
  return (ushort)(u >> 16);
}
__device__ __forceinline__ bf16x8 ld_g16(const ushort* p) {   // 16B global load
  union { uint4 u; bf16x8 v; } r; r.u = *(const uint4*)p; return r.v;
}
__device__ __forceinline__ bf16x8 ld_lds8x2(const ushort* p) { // 2x ds_read_b64
  union { uint2 u[2]; bf16x8 v; } r;
  r.u[0] = *(const uint2*)p;
  r.u[1] = *(const uint2*)(p + 4);
  return r.v;
}

// ---------------------------------------------------------------------------
// Mega prep kernel: all 6 weight transposes (fp32 [K,N] -> bf16 [N,K]),
// bias concat, and pos slice in ONE dispatch (was 8 dispatches/iteration).
// Blocks 0..12287: one 32x32 transpose tile each.  Block 12288: extras.
// ---------------------------------------------------------------------------
__global__ __launch_bounds__(256) void prep_kernel(
    const float* __restrict__ wq, const float* __restrict__ wk,
    const float* __restrict__ wv, const float* __restrict__ wo,
    const float* __restrict__ w1, const float* __restrict__ w2,
    const float* __restrict__ bq, const float* __restrict__ bk,
    const float* __restrict__ bv_, const float* __restrict__ pos,
    ushort* __restrict__ wqkv_t, ushort* __restrict__ wo_t,
    ushort* __restrict__ w1_t, ushort* __restrict__ w2_t,
    float* __restrict__ bqkv, ushort* __restrict__ pos_bf) {
  int id = blockIdx.x;
  if (id < 12288) {
    const float* src; ushort* dst; int K, N, tile;
    if (id < 4096) {
      K = 1024; N = 1024; tile = id & 1023;
      int m = id >> 10;  // 0:wq 1:wk 2:wv 3:wo
      src = (m == 0) ? wq : (m == 1) ? wk : (m == 2) ? wv : wo;
      dst = (m == 3) ? wo_t : wqkv_t + (size_t)m * 1024 * 1024;
    } else if (id < 8192) {
      K = 1024; N = 4096; tile = id - 4096; src = w1; dst = w1_t;
    } else {
      K = 4096; N = 1024; tile = id - 8192; src = w2; dst = w2_t;
    }
    int nx = N >> 5;
    int nb = (tile % nx) * 32, kb = (tile / nx) * 32;
    __shared__ float t32[32][33];
    int tx = threadIdx.x & 31, ty = threadIdx.x >> 5;   // 32 x 8
#pragma unroll
    for (int i = 0; i < 4; ++i)
      t32[ty + i * 8][tx] = src[(size_t)(kb + ty + i * 8) * N + nb + tx];
    __syncthreads();
#pragma unroll
    for (int i = 0; i < 4; ++i)
      dst[(size_t)(nb + ty + i * 8) * K + kb + tx] = f2b(t32[tx][ty + i * 8]);
  } else {
    int t = threadIdx.x;
    for (int i = t; i < 1024; i += 256) {
      bqkv[i] = bq[i]; bqkv[1024 + i] = bk[i]; bqkv[2048 + i] = bv_[i];
    }
    for (int i = t; i < 12800; i += 256)
      pos_bf[i] = f2b(pos[(size_t)199 * 64 + i]);
  }
}

// ---------------------------------------------------------------------------
// LayerNorm (fp32 in) -> bf16 out.  HAS_TIME: += time[r]*wt[c] + bt[c]
// 4 rows/block, one wave per row: pure shuffle reduce, no LDS/barrier.
// ---------------------------------------------------------------------------
template <int HAS_TIME>
__global__ __launch_bounds__(256) void ln_kernel(
    const float* __restrict__ x, const float* __restrict__ g, const float* __restrict__ be,
    const float* __restrict__ tv, const float* __restrict__ wt, const float* __restrict__ bt,
    ushort* __restrict__ out) {
  int wave = threadIdx.x >> 6, lane = threadIdx.x & 63;
  int r = blockIdx.x * 4 + wave;
  const float4* xr = (const float4*)(x + (size_t)r * H_DIM);
  float4 xv[4];
  float s = 0.f, s2 = 0.f;
#pragma unroll
  for (int k = 0; k < 4; ++k) {
    xv[k] = xr[lane + 64 * k];
    s  += xv[k].x + xv[k].y + xv[k].z + xv[k].w;
    s2 += xv[k].x * xv[k].x + xv[k].y * xv[k].y + xv[k].z * xv[k].z + xv[k].w * xv[k].w;
  }
#pragma unroll
  for (int off = 32; off; off >>= 1) {
    s  += __shfl_xor(s, off);
    s2 += __shfl_xor(s2, off);
  }
  float m    = s * (1.0f / H_DIM);
  float var  = s2 * (1.0f / H_DIM) - m * m;
  float rstd = rsqrtf(var + 1e-5f);
  float tval = HAS_TIME ? tv[r] : 0.0f;
  ushort4* orow = (ushort4*)(out + (size_t)r * H_DIM);
#pragma unroll
  for (int k = 0; k < 4; ++k) {
    float4 gv = ((const float4*)g)[lane + 64 * k];
    float4 bv = ((const float4*)be)[lane + 64 * k];
    float v0 = (xv[k].x - m) * rstd * gv.x + bv.x;
    float v1 = (xv[k].y - m) * rstd * gv.y + bv.y;
    float v2 = (xv[k].z - m) * rstd * gv.z + bv.z;
    float v3 = (xv[k].w - m) * rstd * gv.w + bv.w;
    if (HAS_TIME) {
      float4 wv = ((const float4*)wt)[lane + 64 * k];
      float4 btv = ((const float4*)bt)[lane + 64 * k];
      v0 += tval * wv.x + btv.x;
      v1 += tval * wv.y + btv.y;
      v2 += tval * wv.z + btv.z;
      v3 += tval * wv.w + btv.w;
    }
    ushort4 o;
    o.x = f2b(v0); o.y = f2b(v1); o.z = f2b(v2); o.w = f2b(v3);
    orow[lane + 64 * k] = o;
  }
}

// ---------------------------------------------------------------------------
// Old 128x128 GEMM (kept for FF2 where chunked-M makes 256^2 grids too small)
// XCD-aware column-major chunk swizzle (grid blocks % 8 == 0 at call sites).
// ---------------------------------------------------------------------------
template <int EPI>
__global__ __launch_bounds__(256) void gemm_bt(
    const ushort* __restrict__ A, const ushort* __restrict__ Bt,
    const float* __restrict__ bias, void* __restrict__ Cv,
    const float* __restrict__ resid, int M, int N, int K) {
  __shared__ __align__(16) ushort As[2 * 128 * 32];   // [kh][row][32]
  __shared__ __align__(16) ushort Bs[2 * 128 * 32];
  int t = threadIdx.x;
  int lane = t & 63, wave = t >> 6;
  int wm = wave >> 1, wn = wave & 1;
  int r15 = lane & 15, quad = lane >> 4;
  // XCD swizzle (T1), column-major decode: consecutive swz share bx
  int nwg = gridDim.x * gridDim.y;
  int bid = blockIdx.y * gridDim.x + blockIdx.x;
  int swz = (bid & 7) * (nwg >> 3) + (bid >> 3);
  int by = swz % gridDim.y, bx = swz / gridDim.y;
  size_t row0 = (size_t)by * 128;
  size_t col0 = (size_t)bx * 128;

  int srow = (lane >> 2), scol = (lane & 3) * 8;
  const ushort* ga0 = A  + (row0 + wave * 32 +      srow) * K + scol;
  const ushort* ga1 = A  + (row0 + wave * 32 + 16 + srow) * K + scol;
  const ushort* gb0 = Bt + (col0 + wave * 32 +      srow) * K + scol;
  const ushort* gb1 = Bt + (col0 + wave * 32 + 16 + srow) * K + scol;
  ushort* la0 = As + (wave * 32) * 32;
  ushort* la1 = As + (wave * 32 + 16) * 32;
  ushort* lb0 = Bs + (wave * 32) * 32;
  ushort* lb1 = Bs + (wave * 32 + 16) * 32;

  f32x4 acc[4][4] = {};

  for (int k0 = 0; k0 < K; k0 += 64) {
#pragma unroll
    for (int kh = 0; kh < 2; ++kh) {
      int go = k0 + kh * 32, lo = kh * 4096;
      g2lds16(ga0 + go, la0 + lo);
      g2lds16(ga1 + go, la1 + lo);
      g2lds16(gb0 + go, lb0 + lo);
      g2lds16(gb1 + go, lb1 + lo);
    }
    __syncthreads();
#pragma unroll
    for (int kh = 0; kh < 2; ++kh) {
      bf16x8 af[4], bfr[4];
#pragma unroll
      for (int i = 0; i < 4; ++i)
        af[i] = *(const bf16x8*)&As[kh * 4096 + (wm * 64 + i * 16 + r15) * 32 + quad * 8];
#pragma unroll
      for (int j = 0; j < 4; ++j)
        bfr[j] = *(const bf16x8*)&Bs[kh * 4096 + (wn * 64 + j * 16 + r15) * 32 + quad * 8];
#pragma unroll
      for (int i = 0; i < 4; ++i)
#pragma unroll
        for (int j = 0; j < 4; ++j)
          acc[i][j] = __builtin_amdgcn_mfma_f32_16x16x32_bf16(af[i], bfr[j], acc[i][j], 0, 0, 0);
    }
    __syncthreads();
  }

  int mbase = (int)row0 + wm * 64;
  int nbase = (int)col0 + wn * 64;
  float bb[4];
#pragma unroll
  for (int j = 0; j < 4; ++j) bb[j] = bias[nbase + j * 16 + r15];
#pragma unroll
  for (int i = 0; i < 4; ++i) {
#pragma unroll
    for (int ii = 0; ii < 4; ++ii) {
      int row = mbase + i * 16 + quad * 4 + ii;
      size_t rb = (size_t)row * N + nbase + r15;
#pragma unroll
      for (int j = 0; j < 4; ++j) {   // j innermost: 4 stores share a 128B line
        size_t idx = rb + j * 16;
        float v = acc[i][j][ii] + bb[j];
        if constexpr (EPI == 0) {
          ((ushort*)Cv)[idx] = f2b(v);
        } else if constexpr (EPI == 1) {
          float gl = 0.5f * v * (1.0f + erff(v * 0.70710678118f));
          ((ushort*)Cv)[idx] = f2b(gl);
        } else {
          ((float*)Cv)[idx] = v + resid[idx];
        }
      }
    }
  }
}

// ---------------------------------------------------------------------------
// 256x256 8-phase GEMM (T1+T2+T3+T4+T5), unchanged schedule from round 2
// (best measured variant).  Column-major XCD chunk decode; write-combined
// epilogue (j innermost).
// ---------------------------------------------------------------------------
template <int IB>
__device__ __forceinline__ void mfma_blk(f32x4 (&acc)[8][4],
                                         const bf16x8 (&af)[4], const bf16x8 (&bfr)[4]) {
#pragma unroll
  for (int i = 0; i < 4; ++i)
#pragma unroll
    for (int j = 0; j < 4; ++j)
      acc[IB + i][j] =
          __builtin_amdgcn_mfma_f32_16x16x32_bf16(af[i], bfr[j], acc[IB + i][j], 0, 0, 0);
}

__device__ __forceinline__ bf16x8 rdfrag(const ushort* plane, int r, int quad) {
  // logical (row r, 16B-slot quad) -> physical slot quad ^ ((r>>1)&3)
  return *(const bf16x8*)(plane + r * 32 + ((quad ^ ((r >> 1) & 3)) << 3));
}

__device__ __forceinline__ void read_q0(bf16x8 (&af)[4], bf16x8 (&bfr)[4],
                                        const ushort* pA, const ushort* pB,
                                        int wn1, int r15, int quad) {
#pragma unroll
  for (int j = 0; j < 4; ++j) bfr[j] = rdfrag(pB, wn1 * 64 + j * 16 + r15, quad);
#pragma unroll
  for (int i = 0; i < 4; ++i) af[i] = rdfrag(pA, i * 16 + r15, quad);
}
__device__ __forceinline__ void read_q1(bf16x8 (&af)[4], const ushort* pA,
                                        int r15, int quad) {
#pragma unroll
  for (int i = 0; i < 4; ++i) af[i] = rdfrag(pA, 64 + i * 16 + r15, quad);
}

#define VMW8() asm volatile("s_waitcnt vmcnt(8)" ::: "memory")
#define VMW4() asm volatile("s_waitcnt vmcnt(4)" ::: "memory")
#define VMW0() asm volatile("s_waitcnt vmcnt(0)" ::: "memory")
#define BARX() __builtin_amdgcn_s_barrier()
#define PRIO1() __builtin_amdgcn_s_setprio(1)
#define PRIO0() __builtin_amdgcn_s_setprio(0)

template <int EPI>
__global__ __launch_bounds__(512) void gemm256(
    const ushort* __restrict__ A, const ushort* __restrict__ Bt,
    const float* __restrict__ bias, void* __restrict__ Cv,
    const float* __restrict__ resid, int M, int N, int K) {
  __shared__ __align__(16) ushort lds[2][2][2][2][4096];  // [buf][A/B][half][kh][128*32]
  const int t = threadIdx.x;
  const int lane = t & 63, wave = t >> 6;
  const int wm = wave >> 2;            // A half this wave consumes
  const int wn = wave & 3;
  const int wn1 = wn & 1;
  const int bh = wn >> 1;              // B half this wave consumes
  const int r15 = lane & 15, quad = lane >> 4;
  // XCD swizzle (T1), column-major decode: consecutive swz share bx
  int nwg = gridDim.x * gridDim.y;
  int bid = blockIdx.y * gridDim.x + blockIdx.x;
  int swz = (bid & 7) * (nwg >> 3) + (bid >> 3);
  int by = swz % gridDim.y, bx = swz / gridDim.y;
  const size_t row0 = (size_t)by * 256;
  const size_t col0 = (size_t)bx * 256;

  // stage-group indices: 4 waves per A-half, 4 waves per B-half
  const int gwA = wave & 3;
  const int gwB = ((wave >> 1) & 2) | (wave & 1);

  // per-lane pre-swizzled global source pointers (k offset added at issue)
  const ushort *gA0, *gA1, *gB0, *gB1;
  {
    int p0 = gwA * 128 + lane;
    int p1 = p0 + 64;
    int ra0 = p0 >> 2, sa0 = (p0 & 3) ^ ((p0 >> 3) & 3);
    int ra1 = p1 >> 2, sa1 = (p1 & 3) ^ ((p1 >> 3) & 3);
    gA0 = A + (row0 + wm * 128 + ra0) * K + sa0 * 8;
    gA1 = A + (row0 + wm * 128 + ra1) * K + sa1 * 8;
    int q0 = gwB * 128 + lane;
    int q1 = q0 + 64;
    int rb0 = q0 >> 2, sb0 = (q0 & 3) ^ ((q0 >> 3) & 3);
    int rb1 = q1 >> 2, sb1 = (q1 & 3) ^ ((q1 >> 3) & 3);
    gB0 = Bt + (col0 + bh * 128 + rb0) * K + sb0 * 8;
    gB1 = Bt + (col0 + bh * 128 + rb1) * K + sb1 * 8;
  }
  const int ldsA0 = gwA * 1024, ldsA1 = gwA * 1024 + 512;   // ushort offsets
  const int ldsB0 = gwB * 1024, ldsB1 = gwB * 1024 + 512;

#define STAGE_A(nb_, skh_, kof_)                                        \
  do {                                                                  \
    g2lds16(gA0 + (kof_) + (skh_) * 32, &lds[nb_][0][wm][skh_][ldsA0]); \
    g2lds16(gA1 + (kof_) + (skh_) * 32, &lds[nb_][0][wm][skh_][ldsA1]); \
  } while (0)
#define STAGE_B(nb_, skh_, kof_)                                        \
  do {                                                                  \
    g2lds16(gB0 + (kof_) + (skh_) * 32, &lds[nb_][1][bh][skh_][ldsB0]); \
    g2lds16(gB1 + (kof_) + (skh_) * 32, &lds[nb_][1][bh][skh_][ldsB1]); \
  } while (0)
#define PAP(b_, k_) (&lds[b_][0][wm][k_][0])
#define PBP(b_, k_) (&lds[b_][1][bh][k_][0])

  f32x4 acc[8][4] = {};

  // prologue: tile0 full + tile1 kh0 (6 stage ops = 12 loads/thread)
  STAGE_A(0, 0, 0);
  STAGE_B(0, 0, 0);
  STAGE_A(0, 1, 0);
  STAGE_B(0, 1, 0);
  STAGE_A(1, 0, 64);
  STAGE_B(1, 0, 64);
  VMW8();                       // tile0 kh0 (A,B) resident; 8 loads in flight
  BARX();

#define ITER_BODY(LAST_, ka_)                                                  \
  {                                                                            \
    bf16x8 af[4], bfr[4];                                                      \
    /* P0: buf0 kh0 Q0 */                                                      \
    read_q0(af, bfr, PAP(0, 0), PBP(0, 0), wn1, r15, quad);                    \
    STAGE_A(1, 1, (ka_) + 64);                                                 \
    BARX(); PRIO1(); mfma_blk<0>(acc, af, bfr); PRIO0(); BARX();               \
    /* P1: buf0 kh0 Q1 */                                                      \
    read_q1(af, PAP(0, 0), r15, quad);                                         \
    STAGE_B(1, 1, (ka_) + 64);                                                 \
    BARX(); PRIO1(); mfma_blk<4>(acc, af, bfr); PRIO0();                       \
    VMW8(); BARX();                                                            \
    /* P2: buf0 kh1 Q0 */                                                      \
    read_q0(af, bfr, PAP(0, 1), PBP(0, 1), wn1, r15, quad);                    \
    if (!(LAST_)) STAGE_A(0, 0, (ka_) + 128);                                  \
    BARX(); PRIO1(); mfma_blk<0>(acc, af, bfr); PRIO0(); BARX();               \
    /* P3: buf0 kh1 Q1 */                                                      \
    read_q1(af, PAP(0, 1), r15, quad);                                         \
    if (!(LAST_)) STAGE_B(0, 0, (ka_) + 128);                                  \
    BARX(); PRIO1(); mfma_blk<4>(acc, af, bfr); PRIO0();                       \
    if (LAST_) { VMW4(); } else { VMW8(); }                                    \
    BARX();                                                                    \
    /* P4: buf1 kh0 Q0 */                                                      \
    read_q0(af, bfr, PAP(1, 0), PBP(1, 0), wn1, r15, quad);                    \
    if (!(LAST_)) STAGE_A(0, 1, (ka_) + 128);                                  \
    BARX(); PRIO1(); mfma_blk<0>(acc, af, bfr); PRIO0(); BARX();               \
    /* P5: buf1 kh0 Q1 */                                                      \
    read_q1(af, PAP(1, 0), r15, quad);                                         \
    if (!(LAST_)) STAGE_B(0, 1, (ka_) + 128);                                  \
    BARX(); PRIO1(); mfma_blk<4>(acc, af, bfr); PRIO0();                       \
    if (LAST_) { VMW0(); } else { VMW8(); }                                    \
    BARX();                                                                    \
    /* P6: buf1 kh1 Q0 */                                                      \
    read_q0(af, bfr, PAP(1, 1), PBP(1, 1), wn1, r15, quad);                    \
    if (!(LAST_)) STAGE_A(1, 0, (ka_) + 192);                                  \
    BARX(); PRIO1(); mfma_blk<0>(acc, af, bfr); PRIO0(); BARX();               \
    /* P7: buf1 kh1 Q1 */                                                      \
    read_q1(af, PAP(1, 1), r15, quad);                                         \
    if (!(LAST_)) STAGE_B(1, 0, (ka_) + 192);                                  \
    BARX(); PRIO1(); mfma_blk<4>(acc, af, bfr); PRIO0();                       \
    if (!(LAST_)) { VMW8(); }                                                  \
    BARX();                                                                    \
  }

  const int NI = K >> 7;   // two 64-wide K-tiles per iteration
  for (int it = 0; it < NI - 1; ++it) {
    ITER_BODY(0, it << 7);
  }
  ITER_BODY(1, (NI - 1) << 7);
#undef ITER_BODY

  // epilogue (write-combined: j innermost so 4 stores share a 128B line)
  int mbase = (int)row0 + wm * 128;
  int nbase = (int)col0 + wn * 64;
  float bb[4];
#pragma unroll
  for (int j = 0; j < 4; ++j) bb[j] = bias[nbase + j * 16 + r15];
#pragma unroll
  for (int i = 0; i < 8; ++i) {
#pragma unroll
    for (int ii = 0; ii < 4; ++ii) {
      int row = mbase + i * 16 + quad * 4 + ii;
      size_t rb = (size_t)row * N + nbase + r15;
#pragma unroll
      for (int j = 0; j < 4; ++j) {
        size_t idx = rb + j * 16;
        float v = acc[i][j][ii] + bb[j];
        if constexpr (EPI == 0) {
          ((ushort*)Cv)[idx] = f2b(v);
        } else if constexpr (EPI == 1) {
          float gl = 0.5f * v * (1.0f + erff(v * 0.70710678118f));
          ((ushort*)Cv)[idx] = f2b(gl);
        } else {
          ((float*)Cv)[idx] = v + resid[idx];
        }
      }
    }
  }
#undef STAGE_A
#undef STAGE_B
#undef PAP
#undef PBP
}

// ---------------------------------------------------------------------------
// MFMA attention.  One block (4 waves) per (b,h).
// scores = (Q@K^T)*0.125 + T[q, q-k],  T = Q@P^T  (P = pos_bf, rows d=q-k).
// Wave->qt remap balances per-wave work (sum qt+1): {25,22,23,21} vs {28,...}.
// ---------------------------------------------------------------------------
#define PW_STRIDE 228   // elems per row; 456B: 8B-aligned (b64 reads), ~4-way banks
__global__ __launch_bounds__(256) void attn_kernel(
    const ushort* __restrict__ qkv, const ushort* __restrict__ pos_bf,
    ushort* __restrict__ ctx) {
  int bh = blockIdx.x;
  int b = bh >> 4, h = bh & 15;
  __shared__ ushort Vt[64][PW_STRIDE];       // V^T: Vt[d][k]
  __shared__ ushort Pw[4][16][PW_STRIDE];    // per-wave: T strip, then exp(S)
  int t = threadIdx.x, lane = t & 63, wave = t >> 6;
  int r15 = lane & 15, quad = lane >> 4;
  const size_t base = ((size_t)b * S_LEN) * 3072 + (size_t)h * 64;

  // zero Vt pad cols 200..227
  for (int i = t; i < 64 * 28; i += 256) Vt[i / 28][200 + (i % 28)] = 0;
  // stage V transposed
  for (int i = t; i < 800; i += 256) {
    int kp = i >> 3, d0 = (i & 7) * 8;
    int k = kp * 2;
    union { uint4 v; ushort u[8]; } r0, r1;
    r0.v = *(const uint4*)&qkv[base + (size_t)k * 3072 + 2048 + d0];
    r1.v = *(const uint4*)&qkv[base + (size_t)(k + 1) * 3072 + 2048 + d0];
#pragma unroll
    for (int j = 0; j < 8; ++j) {
      ushort2 w2; w2.x = r0.u[j]; w2.y = r1.u[j];
      *(ushort2*)&Vt[d0 + j][k] = w2;
    }
  }
  __syncthreads();

  for (int idx = wave; idx < 13; idx += 4) {
    int qt = (int)((0x3421058769ABCull >> (4 * idx)) & 0xFull);
    int q0 = qt * 16;
    int qrow = q0 + r15; if (qrow > 199) qrow = 199;
    const ushort* qp = qkv + base + (size_t)qrow * 3072;
    bf16x8 aq0 = ld_g16(qp + quad * 8);
    bf16x8 aq1 = ld_g16(qp + 32 + quad * 8);
    ushort* pw = &Pw[wave][0][0];

    // ---- Phase 1: T strip = Q @ P^T ----
#pragma unroll
    for (int dt = 0; dt < 13; ++dt) {
      if (dt > qt) continue;
      int prow = dt * 16 + r15; if (prow > 199) prow = 199;
      const ushort* pp = pos_bf + (size_t)prow * 64;
      bf16x8 p0 = ld_g16(pp + quad * 8);
      bf16x8 p1 = ld_g16(pp + 32 + quad * 8);
      f32x4 tt = {};
      tt = __builtin_amdgcn_mfma_f32_16x16x32_bf16(aq0, p0, tt, 0, 0, 0);
      tt = __builtin_amdgcn_mfma_f32_16x16x32_bf16(aq1, p1, tt, 0, 0, 0);
#pragma unroll
      for (int ii = 0; ii < 4; ++ii)
        pw[(quad * 4 + ii) * PW_STRIDE + dt * 16 + r15] = f2b(tt[ii]);
    }

    // ---- Phase 2: scores ----
    f32x4 sreg[13];
    float rowmax[4] = {-3.0e38f, -3.0e38f, -3.0e38f, -3.0e38f};
#pragma unroll
    for (int kt = 0; kt < 13; ++kt) {
      if (kt > qt) continue;
      int krow = kt * 16 + r15; if (krow > 199) krow = 199;
      const ushort* kp = qkv + base + (size_t)krow * 3072 + 1024;
      bf16x8 k0 = ld_g16(kp + quad * 8);
      bf16x8 k1 = ld_g16(kp + 32 + quad * 8);
      f32x4 s = {};
      s = __builtin_amdgcn_mfma_f32_16x16x32_bf16(aq0, k0, s, 0, 0, 0);
      s = __builtin_amdgcn_mfma_f32_16x16x32_bf16(aq1, k1, s, 0, 0, 0);
      int k = kt * 16 + r15;
#pragma unroll
      for (int ii = 0; ii < 4; ++ii) {
        int q = q0 + quad * 4 + ii;
        float v;
        if (k <= q) {
          v = s[ii] * 0.125f + b2f(pw[(quad * 4 + ii) * PW_STRIDE + (q - k)]);
        } else {
          v = -1.0e30f;
        }
        s[ii] = v;
        rowmax[ii] = fmaxf(rowmax[ii], v);
      }
      sreg[kt] = s;
    }
#pragma unroll
    for (int off = 8; off; off >>= 1)
#pragma unroll
      for (int ii = 0; ii < 4; ++ii)
        rowmax[ii] = fmaxf(rowmax[ii], __shfl_xor(rowmax[ii], off));

    float rsum[4] = {0.f, 0.f, 0.f, 0.f};
#pragma unroll
    for (int kt = 0; kt < 13; ++kt) {
      if (kt > qt) continue;
#pragma unroll
      for (int ii = 0; ii < 4; ++ii) {
        float e = __expf(sreg[kt][ii] - rowmax[ii]);
        rsum[ii] += e;
        pw[(quad * 4 + ii) * PW_STRIDE + kt * 16 + r15] = f2b(e);
      }
    }
    if ((qt & 1) == 0) {
#pragma unroll
      for (int ii = 0; ii < 4; ++ii)
        pw[(quad * 4 + ii) * PW_STRIDE + (qt + 1) * 16 + r15] = 0;
    }
#pragma unroll
    for (int off = 8; off; off >>= 1)
#pragma unroll
      for (int ii = 0; ii < 4; ++ii)
        rsum[ii] += __shfl_xor(rsum[ii], off);
    float rinv[4];
#pragma unroll
    for (int ii = 0; ii < 4; ++ii) rinv[ii] = 1.0f / rsum[ii];

    // ---- Phase 3: ctx = exp(S) @ V ----
    int nk = (q0 + 15) / 32 + 1;
    f32x4 acc[4] = {};
#pragma unroll
    for (int k32 = 0; k32 < 7; ++k32) {
      if (k32 >= nk) continue;
      bf16x8 ap = ld_lds8x2(&pw[r15 * PW_STRIDE + k32 * 32 + quad * 8]);
#pragma unroll
      for (int n = 0; n < 4; ++n) {
        bf16x8 bv = ld_lds8x2(&Vt[n * 16 + r15][k32 * 32 + quad * 8]);
        acc[n] = __builtin_amdgcn_mfma_f32_16x16x32_bf16(ap, bv, acc[n], 0, 0, 0);
      }
    }
#pragma unroll
    for (int n = 0; n < 4; ++n)
#pragma unroll
      for (int ii = 0; ii < 4; ++ii) {
        int q = q0 + quad * 4 + ii;
        if (q < S_LEN)
          ctx[((size_t)(b * S_LEN + q)) * H_DIM + h * 64 + n * 16 + r15] =
              f2b(acc[n][ii] * rinv[ii]);
      }
  }
}

// ---------------------------------------------------------------------------
// Launcher.  Workspace layout (aliased; peak ~124 MB):
//   [weights bf16^T: 25.2 MB][pos_bf 25.6KB][qkv 78.6 MB -> h2+gelu chunk]
//   [hbf 26.2 MB -> ctx]          res2 lives in d_out (fp32, 52.4 MB).
// ---------------------------------------------------------------------------
extern "C" void kernel_launch(void* const* d_in, const int* in_sizes, int n_in,
                              void* d_out, int out_size, void* d_ws, size_t ws_size,
                              hipStream_t stream) {
  (void)in_sizes; (void)n_in; (void)out_size; (void)ws_size;
  const float* x    = (const float*)d_in[0];
  const float* timev= (const float*)d_in[1];
  const float* wq   = (const float*)d_in[2];
  const float* bq   = (const float*)d_in[3];
  const float* wk   = (const float*)d_in[4];
  const float* bk   = (const float*)d_in[5];
  const float* wv   = (const float*)d_in[6];
  const float* bv   = (const float*)d_in[7];
  const float* wo   = (const float*)d_in[8];
  const float* bo   = (const float*)d_in[9];
  const float* wt   = (const float*)d_in[10];
  const float* bt   = (const float*)d_in[11];
  const float* pos  = (const float*)d_in[12];
  const float* g1   = (const float*)d_in[13];
  const float* be1  = (const float*)d_in[14];
  const float* g2   = (const float*)d_in[15];
  const float* be2  = (const float*)d_in[16];
  const float* w1   = (const float*)d_in[17];
  const float* bf1  = (const float*)d_in[18];
  const float* w2   = (const float*)d_in[19];
  const float* bf2  = (const float*)d_in[20];

  char* ws = (char*)d_ws;
  ushort* wqkv_t = (ushort*)ws;   ws += (size_t)3072 * 1024 * 2;   //  6.29 MB
  ushort* wo_t   = (ushort*)ws;   ws += (size_t)1024 * 1024 * 2;   //  2.10 MB
  ushort* w1_t   = (ushort*)ws;   ws += (size_t)4096 * 1024 * 2;   //  8.39 MB
  ushort* w2_t   = (ushort*)ws;   ws += (size_t)1024 * 4096 * 2;   //  8.39 MB
  float*  bqkv   = (float*)ws;    ws += (size_t)16384;             //  16 KB
  ushort* pos_bf = (ushort*)ws;   ws += (size_t)200 * 64 * 2;      //  25.6 KB
  // region R1: qkv during attention; afterwards h2 + gelu chunk
  char* r1 = ws;                  ws += (size_t)NROWS * 3072 * 2;  // 78.64 MB
  ushort* qkv  = (ushort*)r1;
  ushort* h2   = (ushort*)r1;                                      // 26.21 MB
  ushort* gbuf = (ushort*)(r1 + (size_t)NROWS * H_DIM * 2);        // 52.43 MB
  // region R2: hbf, then ctx
  char* r2 = ws;                  ws += (size_t)NROWS * 1024 * 2;  // 26.21 MB
  ushort* hbf = (ushort*)r2;
  ushort* ctx = (ushort*)r2;
  float* res2 = (float*)d_out;

  // one prep dispatch: 6 transposes + bias concat + pos slice
  prep_kernel<<<12289, 256, 0, stream>>>(wq, wk, wv, wo, w1, w2, bq, bk, bv, pos,
                                         wqkv_t, wo_t, w1_t, w2_t, bqkv, pos_bf);

  // LN1 + time embed -> hbf (bf16)
  ln_kernel<1><<<NROWS / 4, 256, 0, stream>>>(x, g1, be1, timev, wt, bt, hbf);

  // fused QKV GEMM: [12800,1024] x [3072,1024]^T -> qkv bf16   (256^2 8-phase)
  gemm256<0><<<dim3(12, 50), 512, 0, stream>>>(hbf, wqkv_t, bqkv, qkv, nullptr,
                                               NROWS, 3072, 1024);
  // MFMA attention: qkv -> ctx (overwrites hbf region; hbf is dead now)
  attn_kernel<<<B_SZ * NHEAD, 256, 0, stream>>>(qkv, pos_bf, ctx);

  // out = ctx @ wo + bo + x   (fp32, into d_out as res2)
  gemm256<2><<<dim3(4, 50), 512, 0, stream>>>(ctx, wo_t, bo, res2, x,
                                              NROWS, 1024, 1024);
  // LN2 -> h2 (bf16, overwrites qkv region; qkv is dead now)
  ln_kernel<0><<<NROWS / 4, 256, 0, stream>>>(res2, g2, be2, nullptr, nullptr, nullptr, h2);

  // FF in 2 row-chunks of 6400 (gelu buffer fits in the freed qkv region)
  for (int c = 0; c < 2; ++c) {
    size_t ro = (size_t)c * 6400;
    gemm256<1><<<dim3(16, 25), 512, 0, stream>>>(h2 + ro * 1024, w1_t, bf1, gbuf, nullptr,
                                                 6400, 4096, 1024);
    gemm_bt<2><<<dim3(8, 50), 256, 0, stream>>>(gbuf, w2_t, bf2, (float*)d_out + ro * 1024,
                                                res2 + ro * 1024, 6400, 1024, 4096);
  }
}

// Round 4
// 773.115 us; speedup vs baseline: 1.0527x; 1.0010x over previous
//
#include <hip/hip_runtime.h>

// Problem constants
#define B_SZ   64
#define S_LEN  200
#define H_DIM  1024
#define NHEAD  16
#define HDIM   64
#define FF_DIM 4096
#define NROWS  (B_SZ * S_LEN)   // 12800

typedef __bf16 bf16x8 __attribute__((ext_vector_type(8)));
typedef float  f32x4  __attribute__((ext_vector_type(4)));

#define GLOBAL_AS __attribute__((address_space(1)))
#define LDS_AS    __attribute__((address_space(3)))

__device__ __forceinline__ void g2lds16(const void* g, void* l) {
  __builtin_amdgcn_global_load_lds((const GLOBAL_AS void*)g, (LDS_AS void*)l, 16, 0, 0);
}

__device__ __forceinline__ float b2f(ushort u) {
  return __uint_as_float(((unsigned int)u) << 16);
}
__device__ __forceinline__ ushort f2b(float f) {
  unsigned int u = __float_as_uint(f);
  u += 0x7fffu + ((u >> 16) & 1u);   // RNE
  return (ushort)(u >> 16);
}
__device__ __forceinline__ bf16x8 ld_g16(const ushort* p) {   // 16B global load
  union { uint4 u; bf16x8 v; } r; r.u = *(const uint4*)p; return r.v;
}
__device__ __forceinline__ bf16x8 ld_lds8x2(const ushort* p) { // 2x ds_read_b64
  union { uint2 u[2]; bf16x8 v; } r;
  r.u[0] = *(const uint2*)p;
  r.u[1] = *(const uint2*)(p + 4);
  return r.v;
}

// ---------------------------------------------------------------------------
// Mega prep kernel: all 6 weight transposes (fp32 [K,N] -> bf16 [N,K]),
// bias concat, and pos slice in ONE dispatch (was 8 dispatches/iteration).
// Blocks 0..12287: one 32x32 transpose tile each.  Block 12288: extras.
// ---------------------------------------------------------------------------
__global__ __launch_bounds__(256) void prep_kernel(
    const float* __restrict__ wq, const float* __restrict__ wk,
    const float* __restrict__ wv, const float* __restrict__ wo,
    const float* __restrict__ w1, const float* __restrict__ w2,
    const float* __restrict__ bq, const float* __restrict__ bk,
    const float* __restrict__ bv_, const float* __restrict__ pos,
    ushort* __restrict__ wqkv_t, ushort* __restrict__ wo_t,
    ushort* __restrict__ w1_t, ushort* __restrict__ w2_t,
    float* __restrict__ bqkv, ushort* __restrict__ pos_bf) {
  int id = blockIdx.x;
  if (id < 12288) {
    const float* src; ushort* dst; int K, N, tile;
    if (id < 4096) {
      K = 1024; N = 1024; tile = id & 1023;
      int m = id >> 10;  // 0:wq 1:wk 2:wv 3:wo
      src = (m == 0) ? wq : (m == 1) ? wk : (m == 2) ? wv : wo;
      dst = (m == 3) ? wo_t : wqkv_t + (size_t)m * 1024 * 1024;
    } else if (id < 8192) {
      K = 1024; N = 4096; tile = id - 4096; src = w1; dst = w1_t;
    } else {
      K = 4096; N = 1024; tile = id - 8192; src = w2; dst = w2_t;
    }
    int nx = N >> 5;
    int nb = (tile % nx) * 32, kb = (tile / nx) * 32;
    __shared__ float t32[32][33];
    int tx = threadIdx.x & 31, ty = threadIdx.x >> 5;   // 32 x 8
#pragma unroll
    for (int i = 0; i < 4; ++i)
      t32[ty + i * 8][tx] = src[(size_t)(kb + ty + i * 8) * N + nb + tx];
    __syncthreads();
#pragma unroll
    for (int i = 0; i < 4; ++i)
      dst[(size_t)(nb + ty + i * 8) * K + kb + tx] = f2b(t32[tx][ty + i * 8]);
  } else {
    int t = threadIdx.x;
    for (int i = t; i < 1024; i += 256) {
      bqkv[i] = bq[i]; bqkv[1024 + i] = bk[i]; bqkv[2048 + i] = bv_[i];
    }
    for (int i = t; i < 12800; i += 256)
      pos_bf[i] = f2b(pos[(size_t)199 * 64 + i]);
  }
}

// ---------------------------------------------------------------------------
// LayerNorm (fp32 in) -> bf16 out.  HAS_TIME: += time[r]*wt[c] + bt[c]
// 4 rows/block, one wave per row: pure shuffle reduce, no LDS/barrier.
// ---------------------------------------------------------------------------
template <int HAS_TIME>
__global__ __launch_bounds__(256) void ln_kernel(
    const float* __restrict__ x, const float* __restrict__ g, const float* __restrict__ be,
    const float* __restrict__ tv, const float* __restrict__ wt, const float* __restrict__ bt,
    ushort* __restrict__ out) {
  int wave = threadIdx.x >> 6, lane = threadIdx.x & 63;
  int r = blockIdx.x * 4 + wave;
  const float4* xr = (const float4*)(x + (size_t)r * H_DIM);
  float4 xv[4];
  float s = 0.f, s2 = 0.f;
#pragma unroll
  for (int k = 0; k < 4; ++k) {
    xv[k] = xr[lane + 64 * k];
    s  += xv[k].x + xv[k].y + xv[k].z + xv[k].w;
    s2 += xv[k].x * xv[k].x + xv[k].y * xv[k].y + xv[k].z * xv[k].z + xv[k].w * xv[k].w;
  }
#pragma unroll
  for (int off = 32; off; off >>= 1) {
    s  += __shfl_xor(s, off);
    s2 += __shfl_xor(s2, off);
  }
  float m    = s * (1.0f / H_DIM);
  float var  = s2 * (1.0f / H_DIM) - m * m;
  float rstd = rsqrtf(var + 1e-5f);
  float tval = HAS_TIME ? tv[r] : 0.0f;
  ushort4* orow = (ushort4*)(out + (size_t)r * H_DIM);
#pragma unroll
  for (int k = 0; k < 4; ++k) {
    float4 gv = ((const float4*)g)[lane + 64 * k];
    float4 bv = ((const float4*)be)[lane + 64 * k];
    float v0 = (xv[k].x - m) * rstd * gv.x + bv.x;
    float v1 = (xv[k].y - m) * rstd * gv.y + bv.y;
    float v2 = (xv[k].z - m) * rstd * gv.z + bv.z;
    float v3 = (xv[k].w - m) * rstd * gv.w + bv.w;
    if (HAS_TIME) {
      float4 wv = ((const float4*)wt)[lane + 64 * k];
      float4 btv = ((const float4*)bt)[lane + 64 * k];
      v0 += tval * wv.x + btv.x;
      v1 += tval * wv.y + btv.y;
      v2 += tval * wv.z + btv.z;
      v3 += tval * wv.w + btv.w;
    }
    ushort4 o;
    o.x = f2b(v0); o.y = f2b(v1); o.z = f2b(v2); o.w = f2b(v3);
    orow[lane + 64 * k] = o;
  }
}

// ---------------------------------------------------------------------------
// Old 128x128 GEMM (kept for FF2 where chunked-M makes 256^2 grids too small)
// XCD swizzle, ROW-major decode (round-2 proven: consecutive same-XCD blocks
// share the A-panel -> A stays in that XCD's L2; col-major variant measured
// +72MB FETCH on QKV and thrashes FF2's 52MB A operand).
// ---------------------------------------------------------------------------
template <int EPI>
__global__ __launch_bounds__(256) void gemm_bt(
    const ushort* __restrict__ A, const ushort* __restrict__ Bt,
    const float* __restrict__ bias, void* __restrict__ Cv,
    const float* __restrict__ resid, int M, int N, int K) {
  __shared__ __align__(16) ushort As[2 * 128 * 32];   // [kh][row][32]
  __shared__ __align__(16) ushort Bs[2 * 128 * 32];
  int t = threadIdx.x;
  int lane = t & 63, wave = t >> 6;
  int wm = wave >> 1, wn = wave & 1;
  int r15 = lane & 15, quad = lane >> 4;
  // XCD swizzle (T1), row-major decode: consecutive swz share by (A-panel)
  int nwg = gridDim.x * gridDim.y;
  int bid = blockIdx.y * gridDim.x + blockIdx.x;
  int swz = (bid & 7) * (nwg >> 3) + (bid >> 3);
  int bx = swz % gridDim.x, by = swz / gridDim.x;
  size_t row0 = (size_t)by * 128;
  size_t col0 = (size_t)bx * 128;

  int srow = (lane >> 2), scol = (lane & 3) * 8;
  const ushort* ga0 = A  + (row0 + wave * 32 +      srow) * K + scol;
  const ushort* ga1 = A  + (row0 + wave * 32 + 16 + srow) * K + scol;
  const ushort* gb0 = Bt + (col0 + wave * 32 +      srow) * K + scol;
  const ushort* gb1 = Bt + (col0 + wave * 32 + 16 + srow) * K + scol;
  ushort* la0 = As + (wave * 32) * 32;
  ushort* la1 = As + (wave * 32 + 16) * 32;
  ushort* lb0 = Bs + (wave * 32) * 32;
  ushort* lb1 = Bs + (wave * 32 + 16) * 32;

  f32x4 acc[4][4] = {};

  for (int k0 = 0; k0 < K; k0 += 64) {
#pragma unroll
    for (int kh = 0; kh < 2; ++kh) {
      int go = k0 + kh * 32, lo = kh * 4096;
      g2lds16(ga0 + go, la0 + lo);
      g2lds16(ga1 + go, la1 + lo);
      g2lds16(gb0 + go, lb0 + lo);
      g2lds16(gb1 + go, lb1 + lo);
    }
    __syncthreads();
#pragma unroll
    for (int kh = 0; kh < 2; ++kh) {
      bf16x8 af[4], bfr[4];
#pragma unroll
      for (int i = 0; i < 4; ++i)
        af[i] = *(const bf16x8*)&As[kh * 4096 + (wm * 64 + i * 16 + r15) * 32 + quad * 8];
#pragma unroll
      for (int j = 0; j < 4; ++j)
        bfr[j] = *(const bf16x8*)&Bs[kh * 4096 + (wn * 64 + j * 16 + r15) * 32 + quad * 8];
#pragma unroll
      for (int i = 0; i < 4; ++i)
#pragma unroll
        for (int j = 0; j < 4; ++j)
          acc[i][j] = __builtin_amdgcn_mfma_f32_16x16x32_bf16(af[i], bfr[j], acc[i][j], 0, 0, 0);
    }
    __syncthreads();
  }

  int mbase = (int)row0 + wm * 64;
  int nbase = (int)col0 + wn * 64;
  float bb[4];
#pragma unroll
  for (int j = 0; j < 4; ++j) bb[j] = bias[nbase + j * 16 + r15];
#pragma unroll
  for (int i = 0; i < 4; ++i) {
#pragma unroll
    for (int ii = 0; ii < 4; ++ii) {
      int row = mbase + i * 16 + quad * 4 + ii;
      size_t rb = (size_t)row * N + nbase + r15;
#pragma unroll
      for (int j = 0; j < 4; ++j) {   // j innermost: 4 stores share a 128B line
        size_t idx = rb + j * 16;
        float v = acc[i][j][ii] + bb[j];
        if constexpr (EPI == 0) {
          ((ushort*)Cv)[idx] = f2b(v);
        } else if constexpr (EPI == 1) {
          float gl = 0.5f * v * (1.0f + erff(v * 0.70710678118f));
          ((ushort*)Cv)[idx] = f2b(gl);
        } else {
          ((float*)Cv)[idx] = v + resid[idx];
        }
      }
    }
  }
}

// ---------------------------------------------------------------------------
// 256x256 8-phase GEMM (T1+T2+T3+T4+T5).  Row-major XCD chunk decode
// (round-2 proven FETCH); write-combined epilogue (round-3 proven WRITE).
// ---------------------------------------------------------------------------
template <int IB>
__device__ __forceinline__ void mfma_blk(f32x4 (&acc)[8][4],
                                         const bf16x8 (&af)[4], const bf16x8 (&bfr)[4]) {
#pragma unroll
  for (int i = 0; i < 4; ++i)
#pragma unroll
    for (int j = 0; j < 4; ++j)
      acc[IB + i][j] =
          __builtin_amdgcn_mfma_f32_16x16x32_bf16(af[i], bfr[j], acc[IB + i][j], 0, 0, 0);
}

__device__ __forceinline__ bf16x8 rdfrag(const ushort* plane, int r, int quad) {
  // logical (row r, 16B-slot quad) -> physical slot quad ^ ((r>>1)&3)
  return *(const bf16x8*)(plane + r * 32 + ((quad ^ ((r >> 1) & 3)) << 3));
}

__device__ __forceinline__ void read_q0(bf16x8 (&af)[4], bf16x8 (&bfr)[4],
                                        const ushort* pA, const ushort* pB,
                                        int wn1, int r15, int quad) {
#pragma unroll
  for (int j = 0; j < 4; ++j) bfr[j] = rdfrag(pB, wn1 * 64 + j * 16 + r15, quad);
#pragma unroll
  for (int i = 0; i < 4; ++i) af[i] = rdfrag(pA, i * 16 + r15, quad);
}
__device__ __forceinline__ void read_q1(bf16x8 (&af)[4], const ushort* pA,
                                        int r15, int quad) {
#pragma unroll
  for (int i = 0; i < 4; ++i) af[i] = rdfrag(pA, 64 + i * 16 + r15, quad);
}

#define VMW8() asm volatile("s_waitcnt vmcnt(8)" ::: "memory")
#define VMW4() asm volatile("s_waitcnt vmcnt(4)" ::: "memory")
#define VMW0() asm volatile("s_waitcnt vmcnt(0)" ::: "memory")
#define BARX() __builtin_amdgcn_s_barrier()
#define PRIO1() __builtin_amdgcn_s_setprio(1)
#define PRIO0() __builtin_amdgcn_s_setprio(0)

template <int EPI>
__global__ __launch_bounds__(512) void gemm256(
    const ushort* __restrict__ A, const ushort* __restrict__ Bt,
    const float* __restrict__ bias, void* __restrict__ Cv,
    const float* __restrict__ resid, int M, int N, int K) {
  __shared__ __align__(16) ushort lds[2][2][2][2][4096];  // [buf][A/B][half][kh][128*32]
  const int t = threadIdx.x;
  const int lane = t & 63, wave = t >> 6;
  const int wm = wave >> 2;            // A half this wave consumes
  const int wn = wave & 3;
  const int wn1 = wn & 1;
  const int bh = wn >> 1;              // B half this wave consumes
  const int r15 = lane & 15, quad = lane >> 4;
  // XCD swizzle (T1), row-major decode: consecutive swz share by (A-panel)
  int nwg = gridDim.x * gridDim.y;
  int bid = blockIdx.y * gridDim.x + blockIdx.x;
  int swz = (bid & 7) * (nwg >> 3) + (bid >> 3);
  int bx = swz % gridDim.x, by = swz / gridDim.x;
  const size_t row0 = (size_t)by * 256;
  const size_t col0 = (size_t)bx * 256;

  // stage-group indices: 4 waves per A-half, 4 waves per B-half
  const int gwA = wave & 3;
  const int gwB = ((wave >> 1) & 2) | (wave & 1);

  // per-lane pre-swizzled global source pointers (k offset added at issue)
  const ushort *gA0, *gA1, *gB0, *gB1;
  {
    int p0 = gwA * 128 + lane;
    int p1 = p0 + 64;
    int ra0 = p0 >> 2, sa0 = (p0 & 3) ^ ((p0 >> 3) & 3);
    int ra1 = p1 >> 2, sa1 = (p1 & 3) ^ ((p1 >> 3) & 3);
    gA0 = A + (row0 + wm * 128 + ra0) * K + sa0 * 8;
    gA1 = A + (row0 + wm * 128 + ra1) * K + sa1 * 8;
    int q0 = gwB * 128 + lane;
    int q1 = q0 + 64;
    int rb0 = q0 >> 2, sb0 = (q0 & 3) ^ ((q0 >> 3) & 3);
    int rb1 = q1 >> 2, sb1 = (q1 & 3) ^ ((q1 >> 3) & 3);
    gB0 = Bt + (col0 + bh * 128 + rb0) * K + sb0 * 8;
    gB1 = Bt + (col0 + bh * 128 + rb1) * K + sb1 * 8;
  }
  const int ldsA0 = gwA * 1024, ldsA1 = gwA * 1024 + 512;   // ushort offsets
  const int ldsB0 = gwB * 1024, ldsB1 = gwB * 1024 + 512;

#define STAGE_A(nb_, skh_, kof_)                                        \
  do {                                                                  \
    g2lds16(gA0 + (kof_) + (skh_) * 32, &lds[nb_][0][wm][skh_][ldsA0]); \
    g2lds16(gA1 + (kof_) + (skh_) * 32, &lds[nb_][0][wm][skh_][ldsA1]); \
  } while (0)
#define STAGE_B(nb_, skh_, kof_)                                        \
  do {                                                                  \
    g2lds16(gB0 + (kof_) + (skh_) * 32, &lds[nb_][1][bh][skh_][ldsB0]); \
    g2lds16(gB1 + (kof_) + (skh_) * 32, &lds[nb_][1][bh][skh_][ldsB1]); \
  } while (0)
#define PAP(b_, k_) (&lds[b_][0][wm][k_][0])
#define PBP(b_, k_) (&lds[b_][1][bh][k_][0])

  f32x4 acc[8][4] = {};

  // prologue: tile0 full + tile1 kh0 (6 stage ops = 12 loads/thread)
  STAGE_A(0, 0, 0);
  STAGE_B(0, 0, 0);
  STAGE_A(0, 1, 0);
  STAGE_B(0, 1, 0);
  STAGE_A(1, 0, 64);
  STAGE_B(1, 0, 64);
  VMW8();                       // tile0 kh0 (A,B) resident; 8 loads in flight
  BARX();

#define ITER_BODY(LAST_, ka_)                                                  \
  {                                                                            \
    bf16x8 af[4], bfr[4];                                                      \
    /* P0: buf0 kh0 Q0 */                                                      \
    read_q0(af, bfr, PAP(0, 0), PBP(0, 0), wn1, r15, quad);                    \
    STAGE_A(1, 1, (ka_) + 64);                                                 \
    BARX(); PRIO1(); mfma_blk<0>(acc, af, bfr); PRIO0(); BARX();               \
    /* P1: buf0 kh0 Q1 */                                                      \
    read_q1(af, PAP(0, 0), r15, quad);                                         \
    STAGE_B(1, 1, (ka_) + 64);                                                 \
    BARX(); PRIO1(); mfma_blk<4>(acc, af, bfr); PRIO0();                       \
    VMW8(); BARX();                                                            \
    /* P2: buf0 kh1 Q0 */                                                      \
    read_q0(af, bfr, PAP(0, 1), PBP(0, 1), wn1, r15, quad);                    \
    if (!(LAST_)) STAGE_A(0, 0, (ka_) + 128);                                  \
    BARX(); PRIO1(); mfma_blk<0>(acc, af, bfr); PRIO0(); BARX();               \
    /* P3: buf0 kh1 Q1 */                                                      \
    read_q1(af, PAP(0, 1), r15, quad);                                         \
    if (!(LAST_)) STAGE_B(0, 0, (ka_) + 128);                                  \
    BARX(); PRIO1(); mfma_blk<4>(acc, af, bfr); PRIO0();                       \
    if (LAST_) { VMW4(); } else { VMW8(); }                                    \
    BARX();                                                                    \
    /* P4: buf1 kh0 Q0 */                                                      \
    read_q0(af, bfr, PAP(1, 0), PBP(1, 0), wn1, r15, quad);                    \
    if (!(LAST_)) STAGE_A(0, 1, (ka_) + 128);                                  \
    BARX(); PRIO1(); mfma_blk<0>(acc, af, bfr); PRIO0(); BARX();               \
    /* P5: buf1 kh0 Q1 */                                                      \
    read_q1(af, PAP(1, 0), r15, quad);                                         \
    if (!(LAST_)) STAGE_B(0, 1, (ka_) + 128);                                  \
    BARX(); PRIO1(); mfma_blk<4>(acc, af, bfr); PRIO0();                       \
    if (LAST_) { VMW0(); } else { VMW8(); }                                    \
    BARX();                                                                    \
    /* P6: buf1 kh1 Q0 */                                                      \
    read_q0(af, bfr, PAP(1, 1), PBP(1, 1), wn1, r15, quad);                    \
    if (!(LAST_)) STAGE_A(1, 0, (ka_) + 192);                                  \
    BARX(); PRIO1(); mfma_blk<0>(acc, af, bfr); PRIO0(); BARX();               \
    /* P7: buf1 kh1 Q1 */                                                      \
    read_q1(af, PAP(1, 1), r15, quad);                                         \
    if (!(LAST_)) STAGE_B(1, 0, (ka_) + 192);                                  \
    BARX(); PRIO1(); mfma_blk<4>(acc, af, bfr); PRIO0();                       \
    if (!(LAST_)) { VMW8(); }                                                  \
    BARX();                                                                    \
  }

  const int NI = K >> 7;   // two 64-wide K-tiles per iteration
  for (int it = 0; it < NI - 1; ++it) {
    ITER_BODY(0, it << 7);
  }
  ITER_BODY(1, (NI - 1) << 7);
#undef ITER_BODY

  // epilogue (write-combined: j innermost so 4 stores share a 128B line)
  int mbase = (int)row0 + wm * 128;
  int nbase = (int)col0 + wn * 64;
  float bb[4];
#pragma unroll
  for (int j = 0; j < 4; ++j) bb[j] = bias[nbase + j * 16 + r15];
#pragma unroll
  for (int i = 0; i < 8; ++i) {
#pragma unroll
    for (int ii = 0; ii < 4; ++ii) {
      int row = mbase + i * 16 + quad * 4 + ii;
      size_t rb = (size_t)row * N + nbase + r15;
#pragma unroll
      for (int j = 0; j < 4; ++j) {
        size_t idx = rb + j * 16;
        float v = acc[i][j][ii] + bb[j];
        if constexpr (EPI == 0) {
          ((ushort*)Cv)[idx] = f2b(v);
        } else if constexpr (EPI == 1) {
          float gl = 0.5f * v * (1.0f + erff(v * 0.70710678118f));
          ((ushort*)Cv)[idx] = f2b(gl);
        } else {
          ((float*)Cv)[idx] = v + resid[idx];
        }
      }
    }
  }
#undef STAGE_A
#undef STAGE_B
#undef PAP
#undef PBP
}

// ---------------------------------------------------------------------------
// MFMA attention.  One block (4 waves) per (b,h).
// scores = (Q@K^T)*0.125 + T[q, q-k],  T = Q@P^T  (P = pos_bf, rows d=q-k).
// Wave->qt remap balances per-wave work (sum qt+1): {25,22,23,21} vs {28,...}.
// ---------------------------------------------------------------------------
#define PW_STRIDE 228   // elems per row; 456B: 8B-aligned (b64 reads), ~4-way banks
__global__ __launch_bounds__(256) void attn_kernel(
    const ushort* __restrict__ qkv, const ushort* __restrict__ pos_bf,
    ushort* __restrict__ ctx) {
  int bh = blockIdx.x;
  int b = bh >> 4, h = bh & 15;
  __shared__ ushort Vt[64][PW_STRIDE];       // V^T: Vt[d][k]
  __shared__ ushort Pw[4][16][PW_STRIDE];    // per-wave: T strip, then exp(S)
  int t = threadIdx.x, lane = t & 63, wave = t >> 6;
  int r15 = lane & 15, quad = lane >> 4;
  const size_t base = ((size_t)b * S_LEN) * 3072 + (size_t)h * 64;

  // zero Vt pad cols 200..227
  for (int i = t; i < 64 * 28; i += 256) Vt[i / 28][200 + (i % 28)] = 0;
  // stage V transposed
  for (int i = t; i < 800; i += 256) {
    int kp = i >> 3, d0 = (i & 7) * 8;
    int k = kp * 2;
    union { uint4 v; ushort u[8]; } r0, r1;
    r0.v = *(const uint4*)&qkv[base + (size_t)k * 3072 + 2048 + d0];
    r1.v = *(const uint4*)&qkv[base + (size_t)(k + 1) * 3072 + 2048 + d0];
#pragma unroll
    for (int j = 0; j < 8; ++j) {
      ushort2 w2; w2.x = r0.u[j]; w2.y = r1.u[j];
      *(ushort2*)&Vt[d0 + j][k] = w2;
    }
  }
  __syncthreads();

  for (int idx = wave; idx < 13; idx += 4) {
    int qt = (int)((0x3421058769ABCull >> (4 * idx)) & 0xFull);
    int q0 = qt * 16;
    int qrow = q0 + r15; if (qrow > 199) qrow = 199;
    const ushort* qp = qkv + base + (size_t)qrow * 3072;
    bf16x8 aq0 = ld_g16(qp + quad * 8);
    bf16x8 aq1 = ld_g16(qp + 32 + quad * 8);
    ushort* pw = &Pw[wave][0][0];

    // ---- Phase 1: T strip = Q @ P^T ----
#pragma unroll
    for (int dt = 0; dt < 13; ++dt) {
      if (dt > qt) continue;
      int prow = dt * 16 + r15; if (prow > 199) prow = 199;
      const ushort* pp = pos_bf + (size_t)prow * 64;
      bf16x8 p0 = ld_g16(pp + quad * 8);
      bf16x8 p1 = ld_g16(pp + 32 + quad * 8);
      f32x4 tt = {};
      tt = __builtin_amdgcn_mfma_f32_16x16x32_bf16(aq0, p0, tt, 0, 0, 0);
      tt = __builtin_amdgcn_mfma_f32_16x16x32_bf16(aq1, p1, tt, 0, 0, 0);
#pragma unroll
      for (int ii = 0; ii < 4; ++ii)
        pw[(quad * 4 + ii) * PW_STRIDE + dt * 16 + r15] = f2b(tt[ii]);
    }

    // ---- Phase 2: scores ----
    f32x4 sreg[13];
    float rowmax[4] = {-3.0e38f, -3.0e38f, -3.0e38f, -3.0e38f};
#pragma unroll
    for (int kt = 0; kt < 13; ++kt) {
      if (kt > qt) continue;
      int krow = kt * 16 + r15; if (krow > 199) krow = 199;
      const ushort* kp = qkv + base + (size_t)krow * 3072 + 1024;
      bf16x8 k0 = ld_g16(kp + quad * 8);
      bf16x8 k1 = ld_g16(kp + 32 + quad * 8);
      f32x4 s = {};
      s = __builtin_amdgcn_mfma_f32_16x16x32_bf16(aq0, k0, s, 0, 0, 0);
      s = __builtin_amdgcn_mfma_f32_16x16x32_bf16(aq1, k1, s, 0, 0, 0);
      int k = kt * 16 + r15;
#pragma unroll
      for (int ii = 0; ii < 4; ++ii) {
        int q = q0 + quad * 4 + ii;
        float v;
        if (k <= q) {
          v = s[ii] * 0.125f + b2f(pw[(quad * 4 + ii) * PW_STRIDE + (q - k)]);
        } else {
          v = -1.0e30f;
        }
        s[ii] = v;
        rowmax[ii] = fmaxf(rowmax[ii], v);
      }
      sreg[kt] = s;
    }
#pragma unroll
    for (int off = 8; off; off >>= 1)
#pragma unroll
      for (int ii = 0; ii < 4; ++ii)
        rowmax[ii] = fmaxf(rowmax[ii], __shfl_xor(rowmax[ii], off));

    float rsum[4] = {0.f, 0.f, 0.f, 0.f};
#pragma unroll
    for (int kt = 0; kt < 13; ++kt) {
      if (kt > qt) continue;
#pragma unroll
      for (int ii = 0; ii < 4; ++ii) {
        float e = __expf(sreg[kt][ii] - rowmax[ii]);
        rsum[ii] += e;
        pw[(quad * 4 + ii) * PW_STRIDE + kt * 16 + r15] = f2b(e);
      }
    }
    if ((qt & 1) == 0) {
#pragma unroll
      for (int ii = 0; ii < 4; ++ii)
        pw[(quad * 4 + ii) * PW_STRIDE + (qt + 1) * 16 + r15] = 0;
    }
#pragma unroll
    for (int off = 8; off; off >>= 1)
#pragma unroll
      for (int ii = 0; ii < 4; ++ii)
        rsum[ii] += __shfl_xor(rsum[ii], off);
    float rinv[4];
#pragma unroll
    for (int ii = 0; ii < 4; ++ii) rinv[ii] = 1.0f / rsum[ii];

    // ---- Phase 3: ctx = exp(S) @ V ----
    int nk = (q0 + 15) / 32 + 1;
    f32x4 acc[4] = {};
#pragma unroll
    for (int k32 = 0; k32 < 7; ++k32) {
      if (k32 >= nk) continue;
      bf16x8 ap = ld_lds8x2(&pw[r15 * PW_STRIDE + k32 * 32 + quad * 8]);
#pragma unroll
      for (int n = 0; n < 4; ++n) {
        bf16x8 bv = ld_lds8x2(&Vt[n * 16 + r15][k32 * 32 + quad * 8]);
        acc[n] = __builtin_amdgcn_mfma_f32_16x16x32_bf16(ap, bv, acc[n], 0, 0, 0);
      }
    }
#pragma unroll
    for (int n = 0; n < 4; ++n)
#pragma unroll
      for (int ii = 0; ii < 4; ++ii) {
        int q = q0 + quad * 4 + ii;
        if (q < S_LEN)
          ctx[((size_t)(b * S_LEN + q)) * H_DIM + h * 64 + n * 16 + r15] =
              f2b(acc[n][ii] * rinv[ii]);
      }
  }
}

// ---------------------------------------------------------------------------
// Launcher.  Workspace layout (aliased; peak ~124 MB):
//   [weights bf16^T: 25.2 MB][pos_bf 25.6KB][qkv 78.6 MB -> h2+gelu chunk]
//   [hbf 26.2 MB -> ctx]          res2 lives in d_out (fp32, 52.4 MB).
// ---------------------------------------------------------------------------
extern "C" void kernel_launch(void* const* d_in, const int* in_sizes, int n_in,
                              void* d_out, int out_size, void* d_ws, size_t ws_size,
                              hipStream_t stream) {
  (void)in_sizes; (void)n_in; (void)out_size; (void)ws_size;
  const float* x    = (const float*)d_in[0];
  const float* timev= (const float*)d_in[1];
  const float* wq   = (const float*)d_in[2];
  const float* bq   = (const float*)d_in[3];
  const float* wk   = (const float*)d_in[4];
  const float* bk   = (const float*)d_in[5];
  const float* wv   = (const float*)d_in[6];
  const float* bv   = (const float*)d_in[7];
  const float* wo   = (const float*)d_in[8];
  const float* bo   = (const float*)d_in[9];
  const float* wt   = (const float*)d_in[10];
  const float* bt   = (const float*)d_in[11];
  const float* pos  = (const float*)d_in[12];
  const float* g1   = (const float*)d_in[13];
  const float* be1  = (const float*)d_in[14];
  const float* g2   = (const float*)d_in[15];
  const float* be2  = (const float*)d_in[16];
  const float* w1   = (const float*)d_in[17];
  const float* bf1  = (const float*)d_in[18];
  const float* w2   = (const float*)d_in[19];
  const float* bf2  = (const float*)d_in[20];

  char* ws = (char*)d_ws;
  ushort* wqkv_t = (ushort*)ws;   ws += (size_t)3072 * 1024 * 2;   //  6.29 MB
  ushort* wo_t   = (ushort*)ws;   ws += (size_t)1024 * 1024 * 2;   //  2.10 MB
  ushort* w1_t   = (ushort*)ws;   ws += (size_t)4096 * 1024 * 2;   //  8.39 MB
  ushort* w2_t   = (ushort*)ws;   ws += (size_t)1024 * 4096 * 2;   //  8.39 MB
  float*  bqkv   = (float*)ws;    ws += (size_t)16384;             //  16 KB
  ushort* pos_bf = (ushort*)ws;   ws += (size_t)200 * 64 * 2;      //  25.6 KB
  // region R1: qkv during attention; afterwards h2 + gelu chunk
  char* r1 = ws;                  ws += (size_t)NROWS * 3072 * 2;  // 78.64 MB
  ushort* qkv  = (ushort*)r1;
  ushort* h2   = (ushort*)r1;                                      // 26.21 MB
  ushort* gbuf = (ushort*)(r1 + (size_t)NROWS * H_DIM * 2);        // 52.43 MB
  // region R2: hbf, then ctx
  char* r2 = ws;                  ws += (size_t)NROWS * 1024 * 2;  // 26.21 MB
  ushort* hbf = (ushort*)r2;
  ushort* ctx = (ushort*)r2;
  float* res2 = (float*)d_out;

  // one prep dispatch: 6 transposes + bias concat + pos slice
  prep_kernel<<<12289, 256, 0, stream>>>(wq, wk, wv, wo, w1, w2, bq, bk, bv, pos,
                                         wqkv_t, wo_t, w1_t, w2_t, bqkv, pos_bf);

  // LN1 + time embed -> hbf (bf16)
  ln_kernel<1><<<NROWS / 4, 256, 0, stream>>>(x, g1, be1, timev, wt, bt, hbf);

  // fused QKV GEMM: [12800,1024] x [3072,1024]^T -> qkv bf16   (256^2 8-phase)
  gemm256<0><<<dim3(12, 50), 512, 0, stream>>>(hbf, wqkv_t, bqkv, qkv, nullptr,
                                               NROWS, 3072, 1024);
  // MFMA attention: qkv -> ctx (overwrites hbf region; hbf is dead now)
  attn_kernel<<<B_SZ * NHEAD, 256, 0, stream>>>(qkv, pos_bf, ctx);

  // out = ctx @ wo + bo + x   (fp32, into d_out as res2)
  gemm256<2><<<dim3(4, 50), 512, 0, stream>>>(ctx, wo_t, bo, res2, x,
                                              NROWS, 1024, 1024);
  // LN2 -> h2 (bf16, overwrites qkv region; qkv is dead now)
  ln_kernel<0><<<NROWS / 4, 256, 0, stream>>>(res2, g2, be2, nullptr, nullptr, nullptr, h2);

  // FF in 2 row-chunks of 6400 (gelu buffer fits in the freed qkv region)
  for (int c = 0; c < 2; ++c) {
    size_t ro = (size_t)c * 6400;
    gemm256<1><<<dim3(16, 25), 512, 0, stream>>>(h2 + ro * 1024, w1_t, bf1, gbuf, nullptr,
                                                 6400, 4096, 1024);
    gemm_bt<2><<<dim3(8, 50), 256, 0, stream>>>(gbuf, w2_t, bf2, (float*)d_out + ro * 1024,
                                                res2 + ro * 1024, 6400, 1024, 4096);
  }
}